// Round 10
// baseline (126.801 us; speedup 1.0000x reference)
//
#include <hip/hip_runtime.h>
#include <math.h>

#define NHEADS 16
#define HD 64

typedef __attribute__((ext_vector_type(8))) _Float16 half8;
typedef __attribute__((ext_vector_type(4))) _Float16 half4;
typedef __attribute__((ext_vector_type(4))) float f32x4;
typedef __attribute__((ext_vector_type(16))) float f32x16;
typedef __attribute__((ext_vector_type(4))) unsigned int u32x4;

__device__ inline void load_lds16(const void* g, void* l) {
    __builtin_amdgcn_global_load_lds(
        (const __attribute__((address_space(1))) unsigned int*)g,
        (__attribute__((address_space(3))) unsigned int*)l, 16, 0, 0);
}
__device__ inline void pl32swap(unsigned int& x, unsigned int& y) {
    asm volatile("v_permlane32_swap_b32 %0, %1" : "+v"(x), "+v"(y));
}

// fp32 -> fp16 for x, w_qkv, w_o in ONE launch. Segment by flat index.
#define NX  4194304   // 4096*1024
#define NWQ 3145728   // 3072*1024
#define NWO 1048576   // 1024*1024
__global__ void cvt_all(const float* __restrict__ x, const float* __restrict__ wq,
                        const float* __restrict__ wo, _Float16* __restrict__ xf,
                        _Float16* __restrict__ wqf, _Float16* __restrict__ wof) {
    int i = (blockIdx.x * blockDim.x + threadIdx.x) * 8;
    const float* src; _Float16* dst; int off;
    if (i < NX)            { src = x;  dst = xf;  off = i; }
    else if (i < NX + NWQ) { src = wq; dst = wqf; off = i - NX; }
    else                   { src = wo; dst = wof; off = i - (NX + NWQ); }
    float4 a = *(const float4*)(src + off);
    float4 b = *(const float4*)(src + off + 4);
    half8 h;
    h[0] = (_Float16)a.x; h[1] = (_Float16)a.y; h[2] = (_Float16)a.z; h[3] = (_Float16)a.w;
    h[4] = (_Float16)b.x; h[5] = (_Float16)b.y; h[6] = (_Float16)b.z; h[7] = (_Float16)b.w;
    *(half8*)(dst + off) = h;
}

// ---- shared GEMM core: 128x128 tile, BK=32, f16 MFMA, XCD-swizzled blockIdx ----
#define GEMM_CORE(K)                                                                   \
    __shared__ __align__(1024) unsigned char smem[16384];                              \
    const int tid = threadIdx.x;                                                       \
    const int l = tid & 63, w = tid >> 6;                                              \
    const int wr = w >> 1, wc = w & 1;                                                 \
    const int nwg = gridDim.x * gridDim.y;                                             \
    const int bid = blockIdx.y * gridDim.x + blockIdx.x;                               \
    const int swz = (bid & 7) * (nwg >> 3) + (bid >> 3);                               \
    const int m0 = (swz / gridDim.x) * 128, n0 = (swz % gridDim.x) * 128;              \
    const int srow = tid >> 2;                                                         \
    const int schunk = (tid & 3) ^ ((srow >> 1) & 3);                                  \
    const size_t gA0 = (size_t)(m0 + srow) * K + schunk * 8;                           \
    const size_t gA1 = gA0 + (size_t)64 * K;                                           \
    const size_t gB0 = (size_t)(n0 + srow) * K + schunk * 8;                           \
    const size_t gB1 = gB0 + (size_t)64 * K;                                           \
    unsigned char* ldsW = smem + w * 1024;                                             \
    const int col16 = l & 15, kc = l >> 4;                                             \
    const int ra0 = wr * 64 + col16;                                                   \
    const int offA = ra0 * 64 + ((kc ^ ((ra0 >> 1) & 3)) * 16);                        \
    const int rb0 = wc * 64 + col16;                                                   \
    const int offB = rb0 * 64 + ((kc ^ ((rb0 >> 1) & 3)) * 16);                        \
    f32x4 acc[4][4] = {};                                                              \
    for (int k0 = 0; k0 < K; k0 += 32) {                                               \
        load_lds16(A + gA0 + k0, ldsW + 0);                                            \
        load_lds16(A + gA1 + k0, ldsW + 4096);                                         \
        load_lds16(B + gB0 + k0, ldsW + 8192);                                         \
        load_lds16(B + gB1 + k0, ldsW + 12288);                                       \
        __syncthreads();                                                               \
        half8 af[4], bf[4];                                                            \
        _Pragma("unroll")                                                              \
        for (int m = 0; m < 4; ++m) af[m] = *(const half8*)(smem + offA + m * 1024);   \
        _Pragma("unroll")                                                              \
        for (int n = 0; n < 4; ++n) bf[n] = *(const half8*)(smem + 8192 + offB + n * 1024); \
        _Pragma("unroll")                                                              \
        for (int m = 0; m < 4; ++m)                                                    \
            _Pragma("unroll")                                                          \
            for (int n = 0; n < 4; ++n)                                                \
                acc[m][n] = __builtin_amdgcn_mfma_f32_16x16x32_f16(af[m], bf[n], acc[m][n], 0, 0, 0); \
        __syncthreads();                                                               \
    }

// out[M,N] = A[M,K] @ B[N,K]^T + bias, f32 out
__global__ __launch_bounds__(256, 2) void gemm_o(
    const _Float16* __restrict__ A, const _Float16* __restrict__ B,
    const float* __restrict__ bias, float* __restrict__ C,
    int M, int N, int K) {
    GEMM_CORE(K)
    const int rowb = m0 + wr * 64 + (l >> 4) * 4;
    const int colb = n0 + wc * 64 + col16;
    float bv[4];
    #pragma unroll
    for (int n = 0; n < 4; ++n) bv[n] = bias[colb + n * 16];
    #pragma unroll
    for (int m = 0; m < 4; ++m)
        #pragma unroll
        for (int j = 0; j < 4; ++j) {
            float* crow = C + (size_t)(rowb + m * 16 + j) * N + colb;
            #pragma unroll
            for (int n = 0; n < 4; ++n) crow[n * 16] = acc[m][n][j] + bv[n];
        }
}

// QKV GEMM, fused epilogue -> Qf (scaled 0.125*log2e) / Kf [bh][s][64], VfT [bh][d][s]
#define QSCALE 0.18033688f
__global__ __launch_bounds__(256, 2) void gemm_qkv(
    const _Float16* __restrict__ A, const _Float16* __restrict__ B,
    const float* __restrict__ bias,
    _Float16* __restrict__ Qf, _Float16* __restrict__ Kf,
    _Float16* __restrict__ VfT, int K) {
    GEMM_CORE(K)
    const int rowb = m0 + wr * 64 + (l >> 4) * 4;
    const int colb = n0 + wc * 64 + col16;
    #pragma unroll
    for (int n = 0; n < 4; ++n) {
        int col = colb + n * 16;
        int h = col / 192;
        int rem = col - h * 192;
        int part = rem >> 6, d = rem & 63;   // wave-uniform
        float bv = bias[col];
        #pragma unroll
        for (int m = 0; m < 4; ++m) {
            int r0 = rowb + m * 16;
            int b = r0 >> 11, s0r = r0 & 2047;
            int bh = b * 16 + h;
            if (part == 0) {
                #pragma unroll
                for (int j = 0; j < 4; ++j)
                    Qf[((size_t)bh * 2048 + s0r + j) * 64 + d] =
                        (_Float16)((acc[m][n][j] + bv) * QSCALE);
            } else if (part == 1) {
                #pragma unroll
                for (int j = 0; j < 4; ++j)
                    Kf[((size_t)bh * 2048 + s0r + j) * 64 + d] = (_Float16)(acc[m][n][j] + bv);
            } else {
                half4 pk;
                pk[0] = (_Float16)(acc[m][n][0] + bv);
                pk[1] = (_Float16)(acc[m][n][1] + bv);
                pk[2] = (_Float16)(acc[m][n][2] + bv);
                pk[3] = (_Float16)(acc[m][n][3] + bv);
                *(half4*)&VfT[((size_t)bh * 64 + d) * 2048 + s0r] = pk;
            }
        }
    }
}

// MFMA flash attention, 32x32 f16, in-register P, absolute-score softmax.
// 8 waves/block over 128 q: wave w = q-group (w&3, 32 q) x KV-half (w>>2).
// Per iteration: stage TWO 64-key tiles (one per KV-half), each wave computes its own.
// Partial (O, lsum, mshift) merged additively in LDS at the end.
__global__ __launch_bounds__(512, 4) void mfma_attn(
    const _Float16* __restrict__ Qf, const _Float16* __restrict__ Kf,
    const _Float16* __restrict__ VfT, _Float16* __restrict__ vals) {
    __shared__ __align__(1024) unsigned char smem[65536];
    const int tid = threadIdx.x;
    const int l = tid & 63, w = tid >> 6;
    const int wl = w & 3, hi = w >> 2;
    const int l31 = l & 31, hl = l >> 5;
    const int bh = blockIdx.y, q0 = blockIdx.x * 128;
    const int h = bh & 15, b = bh >> 4;

    half8 qf[4];
    {
        const _Float16* qp = Qf + ((size_t)bh * 2048 + q0 + wl * 32 + l31) * 64 + hl * 8;
        #pragma unroll
        for (int c = 0; c < 4; ++c) qf[c] = *(const half8*)(qp + c * 16);
    }
    f32x16 zvec = {};
    f32x16 o0 = {}, o1 = {};
    float mshift = 0.f, lsum = 0.f;

    const _Float16* Kg = Kf + (size_t)bh * 2048 * 64;
    const _Float16* Vg = VfT + (size_t)bh * 64 * 2048;

    // staging offsets within a 64-key tile (this wave stages tile `hi`)
    int offK[2], offV[2];
    #pragma unroll
    for (int i = 0; i < 2; ++i) {
        int row2 = wl * 8 + i * 4 + (l >> 4);
        int slot = (l & 15) ^ (row2 & 15);
        int row = row2 * 2 + (slot >> 3);
        int chunk = slot & 7;
        offK[i] = row * 64 + chunk * 8;
        offV[i] = row * 2048 + chunk * 8;
    }
    const int sbase = (l31 & 1) * 8;
    const int xr = (l31 >> 1) & 15;
    const int rb0 = (l31 >> 1) * 256;

    // LDS per dbuf half (32KB): K0 @0, K1 @8K, V0 @16K, V1 @24K
    #define STAGE(it, buf)                                                             \
        {                                                                              \
            int kb = ((it) * 2 + hi) * 64;                                             \
            unsigned char* bK = smem + (buf) * 32768 + hi * 8192 + wl * 2048;          \
            unsigned char* bV = bK + 16384;                                            \
            load_lds16(Kg + (size_t)kb * 64 + offK[0], bK);                            \
            load_lds16(Kg + (size_t)kb * 64 + offK[1], bK + 1024);                     \
            load_lds16(Vg + kb + offV[0], bV);                                         \
            load_lds16(Vg + kb + offV[1], bV + 1024);                                  \
        }

    STAGE(0, 0)
    __syncthreads();
    int cur = 0;
    for (int t = 0; t < 16; ++t) {
        if (t + 1 < 16) STAGE(t + 1, cur ^ 1)
        const unsigned char* Ksb = smem + cur * 32768 + hi * 8192;
        const unsigned char* Vsb = Ksb + 16384;

        // ---- S^T = K @ Q^T (absolute scores) ----
        f32x16 s0_, s1_;
        __builtin_amdgcn_s_setprio(1);
        {
            int chOff = ((sbase + hl) ^ xr) << 4;
            half8 k0 = *(const half8*)(Ksb + rb0 + chOff);
            half8 k1 = *(const half8*)(Ksb + rb0 + 4096 + chOff);
            s0_ = __builtin_amdgcn_mfma_f32_32x32x16_f16(k0, qf[0], zvec, 0, 0, 0);
            s1_ = __builtin_amdgcn_mfma_f32_32x32x16_f16(k1, qf[0], zvec, 0, 0, 0);
        }
        #pragma unroll
        for (int kc = 1; kc < 4; ++kc) {
            int chOff = ((sbase + kc * 2 + hl) ^ xr) << 4;
            half8 k0 = *(const half8*)(Ksb + rb0 + chOff);
            half8 k1 = *(const half8*)(Ksb + rb0 + 4096 + chOff);
            s0_ = __builtin_amdgcn_mfma_f32_32x32x16_f16(k0, qf[kc], s0_, 0, 0, 0);
            s1_ = __builtin_amdgcn_mfma_f32_32x32x16_f16(k1, qf[kc], s1_, 0, 0, 0);
        }
        __builtin_amdgcn_s_setprio(0);

        if (__any(mshift != 0.f)) {
            #pragma unroll
            for (int r = 0; r < 16; ++r) { s0_[r] -= mshift; s1_[r] -= mshift; }
        }

        // ---- exp2 + pack + per-lane row-sum ----
        float r0 = 0.f, r1 = 0.f, r2 = 0.f, r3 = 0.f;
        unsigned int a[2][8];
        #pragma unroll
        for (int j = 0; j < 8; ++j) {
            float p0 = __builtin_amdgcn_exp2f(s0_[2 * j]);
            float p1 = __builtin_amdgcn_exp2f(s0_[2 * j + 1]);
            float q0_ = __builtin_amdgcn_exp2f(s1_[2 * j]);
            float q1_ = __builtin_amdgcn_exp2f(s1_[2 * j + 1]);
            r0 += p0; r1 += p1; r2 += q0_; r3 += q1_;
            a[0][j] = __builtin_bit_cast(unsigned int, __builtin_amdgcn_cvt_pkrtz(p0, p1));
            a[1][j] = __builtin_bit_cast(unsigned int, __builtin_amdgcn_cvt_pkrtz(q0_, q1_));
        }
        float rsum = (r0 + r1) + (r2 + r3);

        // ---- overflow guard (repair rare) ----
        if (__any(rsum > 32768.f)) {
            float pmax = s0_[0];
            #pragma unroll
            for (int r = 1; r < 16; ++r) pmax = fmaxf(pmax, s0_[r]);
            #pragma unroll
            for (int r = 0; r < 16; ++r) pmax = fmaxf(pmax, s1_[r]);
            pmax = fmaxf(pmax, __shfl_xor(pmax, 32, 64));
            float d_ = fmaxf(pmax, 0.f);
            float corr = __builtin_amdgcn_exp2f(-d_);
            #pragma unroll
            for (int r = 0; r < 16; ++r) { s0_[r] -= d_; s1_[r] -= d_; }
            #pragma unroll
            for (int r = 0; r < 16; ++r) { o0[r] *= corr; o1[r] *= corr; }
            lsum *= corr;
            mshift += d_;
            r0 = r1 = r2 = r3 = 0.f;
            #pragma unroll
            for (int j = 0; j < 8; ++j) {
                float p0 = __builtin_amdgcn_exp2f(s0_[2 * j]);
                float p1 = __builtin_amdgcn_exp2f(s0_[2 * j + 1]);
                float q0_ = __builtin_amdgcn_exp2f(s1_[2 * j]);
                float q1_ = __builtin_amdgcn_exp2f(s1_[2 * j + 1]);
                r0 += p0; r1 += p1; r2 += q0_; r3 += q1_;
                a[0][j] = __builtin_bit_cast(unsigned int, __builtin_amdgcn_cvt_pkrtz(p0, p1));
                a[1][j] = __builtin_bit_cast(unsigned int, __builtin_amdgcn_cvt_pkrtz(q0_, q1_));
            }
            rsum = (r0 + r1) + (r2 + r3);
        }
        lsum += rsum;

        // ---- P^T B-fragments in-register ----
        #pragma unroll
        for (int c = 0; c < 2; ++c) {
            pl32swap(a[c][0], a[c][2]);
            pl32swap(a[c][1], a[c][3]);
            pl32swap(a[c][4], a[c][6]);
            pl32swap(a[c][5], a[c][7]);
        }

        // ---- O^T += V^T @ P^T ----
        __builtin_amdgcn_s_setprio(1);
        #pragma unroll
        for (int kk = 0; kk < 4; ++kk) {
            u32x4 pw;
            pw.x = a[kk >> 1][(kk & 1) * 4 + 0];
            pw.y = a[kk >> 1][(kk & 1) * 4 + 1];
            pw.z = a[kk >> 1][(kk & 1) * 4 + 2];
            pw.w = a[kk >> 1][(kk & 1) * 4 + 3];
            half8 pf = __builtin_bit_cast(half8, pw);
            int chOff = ((sbase + kk * 2 + hl) ^ xr) << 4;
            half8 v0 = *(const half8*)(Vsb + rb0 + chOff);
            half8 v1 = *(const half8*)(Vsb + rb0 + 4096 + chOff);
            o0 = __builtin_amdgcn_mfma_f32_32x32x16_f16(v0, pf, o0, 0, 0, 0);
            o1 = __builtin_amdgcn_mfma_f32_32x32x16_f16(v1, pf, o1, 0, 0, 0);
        }
        __builtin_amdgcn_s_setprio(0);
        __syncthreads();
        cur ^= 1;
    }

    // ---- merge the two KV-halves (additive; absolute-score scales) ----
    lsum += __shfl_xor(lsum, 32, 64);   // per-q total for this wave's keys
    float* mb = (float*)smem + wl * 2176;  // [34][64] per q-group
    if (hi == 1) {
        #pragma unroll
        for (int r = 0; r < 16; ++r) {
            mb[r * 64 + l] = o0[r];
            mb[(16 + r) * 64 + l] = o1[r];
        }
        mb[32 * 64 + l] = lsum;
        mb[33 * 64 + l] = mshift;
    }
    __syncthreads();
    if (hi == 0) {
        float l1 = mb[32 * 64 + l], m1 = mb[33 * 64 + l];
        float M = fmaxf(mshift, m1);
        float f0 = __builtin_amdgcn_exp2f(mshift - M);
        float f1 = __builtin_amdgcn_exp2f(m1 - M);
        lsum = lsum * f0 + l1 * f1;
        #pragma unroll
        for (int r = 0; r < 16; ++r) {
            o0[r] = o0[r] * f0 + mb[r * 64 + l] * f1;
            o1[r] = o1[r] * f0 + mb[(16 + r) * 64 + l] * f1;
        }
        float inv = 1.f / lsum;
        size_t orow = ((size_t)(b * 2048 + q0 + wl * 32 + l31)) * 1024 + h * 64;
        #pragma unroll
        for (int dc = 0; dc < 2; ++dc) {
            const f32x16* op = dc ? &o1 : &o0;
            #pragma unroll
            for (int rq = 0; rq < 4; ++rq) {
                int d0 = dc * 32 + rq * 8 + hl * 4;
                half4 hv;
                #pragma unroll
                for (int j = 0; j < 4; ++j) hv[j] = (_Float16)((*op)[rq * 4 + j] * inv);
                *(half4*)(vals + orow + d0) = hv;
            }
        }
    }
}

extern "C" void kernel_launch(void* const* d_in, const int* in_sizes, int n_in,
                              void* d_out, int out_size, void* d_ws, size_t ws_size,
                              hipStream_t stream) {
    const float* x     = (const float*)d_in[0];
    const float* w_qkv = (const float*)d_in[1];
    const float* b_qkv = (const float*)d_in[2];
    const float* w_o   = (const float*)d_in[3];
    const float* b_o   = (const float*)d_in[4];
    float* out = (float*)d_out;

    const int B = 2, S = 2048, D = 1024;
    const int M = B * S;          // 4096
    const int N1 = 3 * D;         // 3072
    const int BH = B * NHEADS;    // 32

    _Float16* xf  = (_Float16*)d_ws;                  // [4096,1024]
    _Float16* wqf = xf  + (size_t)M * D;              // [3072,1024]
    _Float16* wof = wqf + (size_t)N1 * D;             // [1024,1024]
    _Float16* Qf  = wof + (size_t)D * D;              // [32,2048,64]
    _Float16* Kf  = Qf  + (size_t)BH * S * HD;
    _Float16* VfT = Kf  + (size_t)BH * S * HD;        // [32,64,2048]
    _Float16* vals = xf;   // reuse x-f16 space after gemm_qkv

    // 0) all f32->f16 conversions in one launch
    cvt_all<<<(NX + NWQ + NWO) / 2048, 256, 0, stream>>>(x, w_qkv, w_o, xf, wqf, wof);

    // 1) fused QKV projection -> f16 attention layouts
    gemm_qkv<<<dim3(N1 / 128, M / 128), 256, 0, stream>>>(xf, wqf, b_qkv, Qf, Kf, VfT, D);

    // 2) MFMA flash attention (32x32 f16, 8-wave KV-split blocks)
    mfma_attn<<<dim3(S / 128, BH), 512, 0, stream>>>(Qf, Kf, VfT, vals);

    // 3) out = vals @ w_o^T + b_o
    gemm_o<<<dim3(D / 128, M / 128), 256, 0, stream>>>(vals, wof, b_o, out, M, D, D);
}

// Round 11
// 114.272 us; speedup vs baseline: 1.1096x; 1.1096x over previous
//
#include <hip/hip_runtime.h>
#include <math.h>

#define NHEADS 16
#define HD 64

typedef __attribute__((ext_vector_type(8))) _Float16 half8;
typedef __attribute__((ext_vector_type(4))) _Float16 half4;
typedef __attribute__((ext_vector_type(4))) float f32x4;
typedef __attribute__((ext_vector_type(16))) float f32x16;
typedef __attribute__((ext_vector_type(4))) unsigned int u32x4;

__device__ inline void load_lds16(const void* g, void* l) {
    __builtin_amdgcn_global_load_lds(
        (const __attribute__((address_space(1))) unsigned int*)g,
        (__attribute__((address_space(3))) unsigned int*)l, 16, 0, 0);
}
__device__ inline void pl32swap(unsigned int& x, unsigned int& y) {
    asm volatile("v_permlane32_swap_b32 %0, %1" : "+v"(x), "+v"(y));
}

// fp32 -> fp16 for x, w_qkv, w_o in ONE launch. Segment by flat index.
#define NX  4194304   // 4096*1024
#define NWQ 3145728   // 3072*1024
#define NWO 1048576   // 1024*1024
__global__ void cvt_all(const float* __restrict__ x, const float* __restrict__ wq,
                        const float* __restrict__ wo, _Float16* __restrict__ xf,
                        _Float16* __restrict__ wqf, _Float16* __restrict__ wof) {
    int i = (blockIdx.x * blockDim.x + threadIdx.x) * 8;
    const float* src; _Float16* dst; int off;
    if (i < NX)            { src = x;  dst = xf;  off = i; }
    else if (i < NX + NWQ) { src = wq; dst = wqf; off = i - NX; }
    else                   { src = wo; dst = wof; off = i - (NX + NWQ); }
    float4 a = *(const float4*)(src + off);
    float4 b = *(const float4*)(src + off + 4);
    half8 h;
    h[0] = (_Float16)a.x; h[1] = (_Float16)a.y; h[2] = (_Float16)a.z; h[3] = (_Float16)a.w;
    h[4] = (_Float16)b.x; h[5] = (_Float16)b.y; h[6] = (_Float16)b.z; h[7] = (_Float16)b.w;
    *(half8*)(dst + off) = h;
}

// ---- shared GEMM core: 128x128 tile, BK=32, f16 MFMA, XCD-swizzled blockIdx ----
#define GEMM_CORE(K)                                                                   \
    __shared__ __align__(1024) unsigned char smem[16384];                              \
    const int tid = threadIdx.x;                                                       \
    const int l = tid & 63, w = tid >> 6;                                              \
    const int wr = w >> 1, wc = w & 1;                                                 \
    const int nwg = gridDim.x * gridDim.y;                                             \
    const int bid = blockIdx.y * gridDim.x + blockIdx.x;                               \
    const int swz = (bid & 7) * (nwg >> 3) + (bid >> 3);                               \
    const int m0 = (swz / gridDim.x) * 128, n0 = (swz % gridDim.x) * 128;              \
    const int srow = tid >> 2;                                                         \
    const int schunk = (tid & 3) ^ ((srow >> 1) & 3);                                  \
    const size_t gA0 = (size_t)(m0 + srow) * K + schunk * 8;                           \
    const size_t gA1 = gA0 + (size_t)64 * K;                                           \
    const size_t gB0 = (size_t)(n0 + srow) * K + schunk * 8;                           \
    const size_t gB1 = gB0 + (size_t)64 * K;                                           \
    unsigned char* ldsW = smem + w * 1024;                                             \
    const int col16 = l & 15, kc = l >> 4;                                             \
    const int ra0 = wr * 64 + col16;                                                   \
    const int offA = ra0 * 64 + ((kc ^ ((ra0 >> 1) & 3)) * 16);                        \
    const int rb0 = wc * 64 + col16;                                                   \
    const int offB = rb0 * 64 + ((kc ^ ((rb0 >> 1) & 3)) * 16);                        \
    f32x4 acc[4][4] = {};                                                              \
    for (int k0 = 0; k0 < K; k0 += 32) {                                               \
        load_lds16(A + gA0 + k0, ldsW + 0);                                            \
        load_lds16(A + gA1 + k0, ldsW + 4096);                                         \
        load_lds16(B + gB0 + k0, ldsW + 8192);                                         \
        load_lds16(B + gB1 + k0, ldsW + 12288);                                       \
        __syncthreads();                                                               \
        half8 af[4], bf[4];                                                            \
        _Pragma("unroll")                                                              \
        for (int m = 0; m < 4; ++m) af[m] = *(const half8*)(smem + offA + m * 1024);   \
        _Pragma("unroll")                                                              \
        for (int n = 0; n < 4; ++n) bf[n] = *(const half8*)(smem + 8192 + offB + n * 1024); \
        _Pragma("unroll")                                                              \
        for (int m = 0; m < 4; ++m)                                                    \
            _Pragma("unroll")                                                          \
            for (int n = 0; n < 4; ++n)                                                \
                acc[m][n] = __builtin_amdgcn_mfma_f32_16x16x32_f16(af[m], bf[n], acc[m][n], 0, 0, 0); \
        __syncthreads();                                                               \
    }

// out[M,N] = A[M,K] @ B[N,K]^T + bias, f32 out
__global__ __launch_bounds__(256, 2) void gemm_o(
    const _Float16* __restrict__ A, const _Float16* __restrict__ B,
    const float* __restrict__ bias, float* __restrict__ C,
    int M, int N, int K) {
    GEMM_CORE(K)
    const int rowb = m0 + wr * 64 + (l >> 4) * 4;
    const int colb = n0 + wc * 64 + col16;
    float bv[4];
    #pragma unroll
    for (int n = 0; n < 4; ++n) bv[n] = bias[colb + n * 16];
    #pragma unroll
    for (int m = 0; m < 4; ++m)
        #pragma unroll
        for (int j = 0; j < 4; ++j) {
            float* crow = C + (size_t)(rowb + m * 16 + j) * N + colb;
            #pragma unroll
            for (int n = 0; n < 4; ++n) crow[n * 16] = acc[m][n][j] + bv[n];
        }
}

// QKV GEMM, fused epilogue -> Qf (scaled 0.125*log2e) / Kf [bh][s][64], VfT [bh][d][s]
#define QSCALE 0.18033688f
__global__ __launch_bounds__(256, 2) void gemm_qkv(
    const _Float16* __restrict__ A, const _Float16* __restrict__ B,
    const float* __restrict__ bias,
    _Float16* __restrict__ Qf, _Float16* __restrict__ Kf,
    _Float16* __restrict__ VfT, int K) {
    GEMM_CORE(K)
    const int rowb = m0 + wr * 64 + (l >> 4) * 4;
    const int colb = n0 + wc * 64 + col16;
    #pragma unroll
    for (int n = 0; n < 4; ++n) {
        int col = colb + n * 16;
        int h = col / 192;
        int rem = col - h * 192;
        int part = rem >> 6, d = rem & 63;   // wave-uniform
        float bv = bias[col];
        #pragma unroll
        for (int m = 0; m < 4; ++m) {
            int r0 = rowb + m * 16;
            int b = r0 >> 11, s0r = r0 & 2047;
            int bh = b * 16 + h;
            if (part == 0) {
                #pragma unroll
                for (int j = 0; j < 4; ++j)
                    Qf[((size_t)bh * 2048 + s0r + j) * 64 + d] =
                        (_Float16)((acc[m][n][j] + bv) * QSCALE);
            } else if (part == 1) {
                #pragma unroll
                for (int j = 0; j < 4; ++j)
                    Kf[((size_t)bh * 2048 + s0r + j) * 64 + d] = (_Float16)(acc[m][n][j] + bv);
            } else {
                half4 pk;
                pk[0] = (_Float16)(acc[m][n][0] + bv);
                pk[1] = (_Float16)(acc[m][n][1] + bv);
                pk[2] = (_Float16)(acc[m][n][2] + bv);
                pk[3] = (_Float16)(acc[m][n][3] + bv);
                *(half4*)&VfT[((size_t)bh * 64 + d) * 2048 + s0r] = pk;
            }
        }
    }
}

// MFMA flash attention, 32x32 f16, in-register P, absolute-score softmax.
// 8 IDENTICAL-role waves per block, q-tile 256 (wave w owns q [w*32, w*32+32)).
// One shared KV stream, KVBLK=64, double-buffered; 1 K-load + 1 V-load per thread.
// Grid (S/256, B*H) remapped so all 8 q-blocks of a head share hwbid%8 (one XCD).
__global__ __launch_bounds__(512, 2) void mfma_attn(
    const _Float16* __restrict__ Qf, const _Float16* __restrict__ Kf,
    const _Float16* __restrict__ VfT, _Float16* __restrict__ vals) {
    __shared__ __align__(1024) unsigned char smem[32768];
    const int tid = threadIdx.x;
    const int l = tid & 63, w = tid >> 6;          // 8 waves
    const int l31 = l & 31, hl = l >> 5;
    // XCD-grouping remap: hwbid = r + 8*(q_t + 8*g) -> bh = r + 8g, q-tile = q_t
    const int hwbid = blockIdx.y * gridDim.x + blockIdx.x;
    const int q_t = (hwbid >> 3) & 7;
    const int bh = (hwbid & 7) + ((hwbid >> 6) << 3);
    const int q0 = q_t * 256;
    const int h = bh & 15, b = bh >> 4;

    half8 qf[4];
    {
        const _Float16* qp = Qf + ((size_t)bh * 2048 + q0 + w * 32 + l31) * 64 + hl * 8;
        #pragma unroll
        for (int c = 0; c < 4; ++c) qf[c] = *(const half8*)(qp + c * 16);
    }
    f32x16 zvec = {};
    f32x16 o0 = {}, o1 = {};
    float mshift = 0.f, lsum = 0.f;

    const _Float16* Kg = Kf + (size_t)bh * 2048 * 64;
    const _Float16* Vg = VfT + (size_t)bh * 64 * 2048;

    // staging: 512 threads cover 32 row-pairs x 16 slots, 1 K + 1 V load each
    int offK, offV;
    {
        int row2 = w * 4 + (l >> 4);               // [0,32)
        int slot = (l & 15) ^ (row2 & 15);
        int row = row2 * 2 + (slot >> 3);
        int chunk = slot & 7;
        offK = row * 64 + chunk * 8;
        offV = row * 2048 + chunk * 8;
    }
    const int sbase = (l31 & 1) * 8;
    const int xr = (l31 >> 1) & 15;
    const int rb0 = (l31 >> 1) * 256;

    // LDS: K0 @0, K1 @8K, V0 @16K, V1 @24K
    #define STAGE(kt0, buf)                                                            \
        {                                                                              \
            unsigned char* bK = smem + (buf) * 8192 + w * 1024;                        \
            unsigned char* bV = smem + 16384 + (buf) * 8192 + w * 1024;                \
            load_lds16(Kg + (size_t)(kt0) * 64 + offK, bK);                            \
            load_lds16(Vg + (kt0) + offV, bV);                                         \
        }

    STAGE(0, 0)
    __syncthreads();
    int cur = 0;
    for (int t = 0; t < 32; ++t) {
        if (t + 1 < 32) STAGE((t + 1) * 64, cur ^ 1)
        const unsigned char* Ksb = smem + cur * 8192;
        const unsigned char* Vsb = smem + 16384 + cur * 8192;

        // ---- S^T = K @ Q^T (absolute scores, C chained off persistent zero) ----
        f32x16 s0_, s1_;
        __builtin_amdgcn_s_setprio(1);
        {
            int chOff = ((sbase + hl) ^ xr) << 4;
            half8 k0 = *(const half8*)(Ksb + rb0 + chOff);
            half8 k1 = *(const half8*)(Ksb + rb0 + 4096 + chOff);
            s0_ = __builtin_amdgcn_mfma_f32_32x32x16_f16(k0, qf[0], zvec, 0, 0, 0);
            s1_ = __builtin_amdgcn_mfma_f32_32x32x16_f16(k1, qf[0], zvec, 0, 0, 0);
        }
        #pragma unroll
        for (int kc = 1; kc < 4; ++kc) {
            int chOff = ((sbase + kc * 2 + hl) ^ xr) << 4;
            half8 k0 = *(const half8*)(Ksb + rb0 + chOff);
            half8 k1 = *(const half8*)(Ksb + rb0 + 4096 + chOff);
            s0_ = __builtin_amdgcn_mfma_f32_32x32x16_f16(k0, qf[kc], s0_, 0, 0, 0);
            s1_ = __builtin_amdgcn_mfma_f32_32x32x16_f16(k1, qf[kc], s1_, 0, 0, 0);
        }
        __builtin_amdgcn_s_setprio(0);

        if (__any(mshift != 0.f)) {
            #pragma unroll
            for (int r = 0; r < 16; ++r) { s0_[r] -= mshift; s1_[r] -= mshift; }
        }

        // ---- exp2 + pack + per-lane row-sum ----
        float r0 = 0.f, r1 = 0.f, r2 = 0.f, r3 = 0.f;
        unsigned int a[2][8];
        #pragma unroll
        for (int j = 0; j < 8; ++j) {
            float p0 = __builtin_amdgcn_exp2f(s0_[2 * j]);
            float p1 = __builtin_amdgcn_exp2f(s0_[2 * j + 1]);
            float q0_ = __builtin_amdgcn_exp2f(s1_[2 * j]);
            float q1_ = __builtin_amdgcn_exp2f(s1_[2 * j + 1]);
            r0 += p0; r1 += p1; r2 += q0_; r3 += q1_;
            a[0][j] = __builtin_bit_cast(unsigned int, __builtin_amdgcn_cvt_pkrtz(p0, p1));
            a[1][j] = __builtin_bit_cast(unsigned int, __builtin_amdgcn_cvt_pkrtz(q0_, q1_));
        }
        float rsum = (r0 + r1) + (r2 + r3);

        // ---- overflow guard: p_max <= rsum; repair path rare ----
        if (__any(rsum > 32768.f)) {
            float pmax = s0_[0];
            #pragma unroll
            for (int r = 1; r < 16; ++r) pmax = fmaxf(pmax, s0_[r]);
            #pragma unroll
            for (int r = 0; r < 16; ++r) pmax = fmaxf(pmax, s1_[r]);
            pmax = fmaxf(pmax, __shfl_xor(pmax, 32, 64));
            float d_ = fmaxf(pmax, 0.f);
            float corr = __builtin_amdgcn_exp2f(-d_);
            #pragma unroll
            for (int r = 0; r < 16; ++r) { s0_[r] -= d_; s1_[r] -= d_; }
            #pragma unroll
            for (int r = 0; r < 16; ++r) { o0[r] *= corr; o1[r] *= corr; }
            lsum *= corr;
            mshift += d_;
            r0 = r1 = r2 = r3 = 0.f;
            #pragma unroll
            for (int j = 0; j < 8; ++j) {
                float p0 = __builtin_amdgcn_exp2f(s0_[2 * j]);
                float p1 = __builtin_amdgcn_exp2f(s0_[2 * j + 1]);
                float q0_ = __builtin_amdgcn_exp2f(s1_[2 * j]);
                float q1_ = __builtin_amdgcn_exp2f(s1_[2 * j + 1]);
                r0 += p0; r1 += p1; r2 += q0_; r3 += q1_;
                a[0][j] = __builtin_bit_cast(unsigned int, __builtin_amdgcn_cvt_pkrtz(p0, p1));
                a[1][j] = __builtin_bit_cast(unsigned int, __builtin_amdgcn_cvt_pkrtz(q0_, q1_));
            }
            rsum = (r0 + r1) + (r2 + r3);
        }
        lsum += rsum;

        // ---- P^T B-fragments in-register ----
        #pragma unroll
        for (int c = 0; c < 2; ++c) {
            pl32swap(a[c][0], a[c][2]);
            pl32swap(a[c][1], a[c][3]);
            pl32swap(a[c][4], a[c][6]);
            pl32swap(a[c][5], a[c][7]);
        }

        // ---- O^T += V^T @ P^T ----
        __builtin_amdgcn_s_setprio(1);
        #pragma unroll
        for (int kk = 0; kk < 4; ++kk) {
            u32x4 pw;
            pw.x = a[kk >> 1][(kk & 1) * 4 + 0];
            pw.y = a[kk >> 1][(kk & 1) * 4 + 1];
            pw.z = a[kk >> 1][(kk & 1) * 4 + 2];
            pw.w = a[kk >> 1][(kk & 1) * 4 + 3];
            half8 pf = __builtin_bit_cast(half8, pw);
            int chOff = ((sbase + kk * 2 + hl) ^ xr) << 4;
            half8 v0 = *(const half8*)(Vsb + rb0 + chOff);
            half8 v1 = *(const half8*)(Vsb + rb0 + 4096 + chOff);
            o0 = __builtin_amdgcn_mfma_f32_32x32x16_f16(v0, pf, o0, 0, 0, 0);
            o1 = __builtin_amdgcn_mfma_f32_32x32x16_f16(v1, pf, o1, 0, 0, 0);
        }
        __builtin_amdgcn_s_setprio(0);
        __syncthreads();
        cur ^= 1;
    }

    // ---- epilogue ----
    lsum += __shfl_xor(lsum, 32, 64);
    float inv = 1.f / lsum;
    size_t orow = ((size_t)(b * 2048 + q0 + w * 32 + l31)) * 1024 + h * 64;
    #pragma unroll
    for (int dc = 0; dc < 2; ++dc) {
        const f32x16* op = dc ? &o1 : &o0;
        #pragma unroll
        for (int rq = 0; rq < 4; ++rq) {
            int d0 = dc * 32 + rq * 8 + hl * 4;
            half4 hv;
            #pragma unroll
            for (int j = 0; j < 4; ++j) hv[j] = (_Float16)((*op)[rq * 4 + j] * inv);
            *(half4*)(vals + orow + d0) = hv;
        }
    }
}

extern "C" void kernel_launch(void* const* d_in, const int* in_sizes, int n_in,
                              void* d_out, int out_size, void* d_ws, size_t ws_size,
                              hipStream_t stream) {
    const float* x     = (const float*)d_in[0];
    const float* w_qkv = (const float*)d_in[1];
    const float* b_qkv = (const float*)d_in[2];
    const float* w_o   = (const float*)d_in[3];
    const float* b_o   = (const float*)d_in[4];
    float* out = (float*)d_out;

    const int B = 2, S = 2048, D = 1024;
    const int M = B * S;          // 4096
    const int N1 = 3 * D;         // 3072
    const int BH = B * NHEADS;    // 32

    _Float16* xf  = (_Float16*)d_ws;                  // [4096,1024]
    _Float16* wqf = xf  + (size_t)M * D;              // [3072,1024]
    _Float16* wof = wqf + (size_t)N1 * D;             // [1024,1024]
    _Float16* Qf  = wof + (size_t)D * D;              // [32,2048,64]
    _Float16* Kf  = Qf  + (size_t)BH * S * HD;
    _Float16* VfT = Kf  + (size_t)BH * S * HD;        // [32,64,2048]
    _Float16* vals = xf;   // reuse x-f16 space after gemm_qkv

    // 0) all f32->f16 conversions in one launch
    cvt_all<<<(NX + NWQ + NWO) / 2048, 256, 0, stream>>>(x, w_qkv, w_o, xf, wqf, wof);

    // 1) fused QKV projection -> f16 attention layouts
    gemm_qkv<<<dim3(N1 / 128, M / 128), 256, 0, stream>>>(xf, wqf, b_qkv, Qf, Kf, VfT, D);

    // 2) MFMA flash attention (32x32 f16, 8 identical waves, q-tile 256, XCD-grouped)
    mfma_attn<<<dim3(S / 256, BH), 512, 0, stream>>>(Qf, Kf, VfT, vals);

    // 3) out = vals @ w_o^T + b_o
    gemm_o<<<dim3(D / 128, M / 128), 256, 0, stream>>>(vals, wof, b_o, out, M, D, D);
}

// Round 12
// 112.888 us; speedup vs baseline: 1.1232x; 1.0123x over previous
//
#include <hip/hip_runtime.h>
#include <math.h>

#define NHEADS 16
#define HD 64

typedef __attribute__((ext_vector_type(8))) _Float16 half8;
typedef __attribute__((ext_vector_type(4))) _Float16 half4;
typedef __attribute__((ext_vector_type(4))) float f32x4;
typedef __attribute__((ext_vector_type(16))) float f32x16;
typedef __attribute__((ext_vector_type(4))) unsigned int u32x4;

__device__ inline void load_lds16(const void* g, void* l) {
    __builtin_amdgcn_global_load_lds(
        (const __attribute__((address_space(1))) unsigned int*)g,
        (__attribute__((address_space(3))) unsigned int*)l, 16, 0, 0);
}
__device__ inline void pl32swap(unsigned int& x, unsigned int& y) {
    asm volatile("v_permlane32_swap_b32 %0, %1" : "+v"(x), "+v"(y));
}

// fp32 -> fp16 for x, w_qkv, w_o in ONE launch. Segment by flat index.
#define NX  4194304   // 4096*1024
#define NWQ 3145728   // 3072*1024
#define NWO 1048576   // 1024*1024
__global__ void cvt_all(const float* __restrict__ x, const float* __restrict__ wq,
                        const float* __restrict__ wo, _Float16* __restrict__ xf,
                        _Float16* __restrict__ wqf, _Float16* __restrict__ wof) {
    int i = (blockIdx.x * blockDim.x + threadIdx.x) * 8;
    const float* src; _Float16* dst; int off;
    if (i < NX)            { src = x;  dst = xf;  off = i; }
    else if (i < NX + NWQ) { src = wq; dst = wqf; off = i - NX; }
    else                   { src = wo; dst = wof; off = i - (NX + NWQ); }
    float4 a = *(const float4*)(src + off);
    float4 b = *(const float4*)(src + off + 4);
    half8 h;
    h[0] = (_Float16)a.x; h[1] = (_Float16)a.y; h[2] = (_Float16)a.z; h[3] = (_Float16)a.w;
    h[4] = (_Float16)b.x; h[5] = (_Float16)b.y; h[6] = (_Float16)b.z; h[7] = (_Float16)b.w;
    *(half8*)(dst + off) = h;
}

// ---- shared GEMM core: 128x128 tile, BK=32, f16 MFMA, XCD-swizzled blockIdx ----
#define GEMM_CORE(K)                                                                   \
    __shared__ __align__(1024) unsigned char smem[16384];                              \
    const int tid = threadIdx.x;                                                       \
    const int l = tid & 63, w = tid >> 6;                                              \
    const int wr = w >> 1, wc = w & 1;                                                 \
    const int nwg = gridDim.x * gridDim.y;                                             \
    const int bid = blockIdx.y * gridDim.x + blockIdx.x;                               \
    const int swz = (bid & 7) * (nwg >> 3) + (bid >> 3);                               \
    const int m0 = (swz / gridDim.x) * 128, n0 = (swz % gridDim.x) * 128;              \
    const int srow = tid >> 2;                                                         \
    const int schunk = (tid & 3) ^ ((srow >> 1) & 3);                                  \
    const size_t gA0 = (size_t)(m0 + srow) * K + schunk * 8;                           \
    const size_t gA1 = gA0 + (size_t)64 * K;                                           \
    const size_t gB0 = (size_t)(n0 + srow) * K + schunk * 8;                           \
    const size_t gB1 = gB0 + (size_t)64 * K;                                           \
    unsigned char* ldsW = smem + w * 1024;                                             \
    const int col16 = l & 15, kc = l >> 4;                                             \
    const int ra0 = wr * 64 + col16;                                                   \
    const int offA = ra0 * 64 + ((kc ^ ((ra0 >> 1) & 3)) * 16);                        \
    const int rb0 = wc * 64 + col16;                                                   \
    const int offB = rb0 * 64 + ((kc ^ ((rb0 >> 1) & 3)) * 16);                        \
    f32x4 acc[4][4] = {};                                                              \
    for (int k0 = 0; k0 < K; k0 += 32) {                                               \
        load_lds16(A + gA0 + k0, ldsW + 0);                                            \
        load_lds16(A + gA1 + k0, ldsW + 4096);                                         \
        load_lds16(B + gB0 + k0, ldsW + 8192);                                         \
        load_lds16(B + gB1 + k0, ldsW + 12288);                                       \
        __syncthreads();                                                               \
        half8 af[4], bf[4];                                                            \
        _Pragma("unroll")                                                              \
        for (int m = 0; m < 4; ++m) af[m] = *(const half8*)(smem + offA + m * 1024);   \
        _Pragma("unroll")                                                              \
        for (int n = 0; n < 4; ++n) bf[n] = *(const half8*)(smem + 8192 + offB + n * 1024); \
        _Pragma("unroll")                                                              \
        for (int m = 0; m < 4; ++m)                                                    \
            _Pragma("unroll")                                                          \
            for (int n = 0; n < 4; ++n)                                                \
                acc[m][n] = __builtin_amdgcn_mfma_f32_16x16x32_f16(af[m], bf[n], acc[m][n], 0, 0, 0); \
        __syncthreads();                                                               \
    }

// out[M,N] = A[M,K] @ B[N,K]^T + bias, f32 out
__global__ __launch_bounds__(256, 2) void gemm_o(
    const _Float16* __restrict__ A, const _Float16* __restrict__ B,
    const float* __restrict__ bias, float* __restrict__ C,
    int M, int N, int K) {
    GEMM_CORE(K)
    const int rowb = m0 + wr * 64 + (l >> 4) * 4;
    const int colb = n0 + wc * 64 + col16;
    float bv[4];
    #pragma unroll
    for (int n = 0; n < 4; ++n) bv[n] = bias[colb + n * 16];
    #pragma unroll
    for (int m = 0; m < 4; ++m)
        #pragma unroll
        for (int j = 0; j < 4; ++j) {
            float* crow = C + (size_t)(rowb + m * 16 + j) * N + colb;
            #pragma unroll
            for (int n = 0; n < 4; ++n) crow[n * 16] = acc[m][n][j] + bv[n];
        }
}

// QKV GEMM, fused epilogue -> Qf (scaled 0.125*log2e) / Kf [bh][s][64], VfT [bh][d][s]
#define QSCALE 0.18033688f
__global__ __launch_bounds__(256, 2) void gemm_qkv(
    const _Float16* __restrict__ A, const _Float16* __restrict__ B,
    const float* __restrict__ bias,
    _Float16* __restrict__ Qf, _Float16* __restrict__ Kf,
    _Float16* __restrict__ VfT, int K) {
    GEMM_CORE(K)
    const int rowb = m0 + wr * 64 + (l >> 4) * 4;
    const int colb = n0 + wc * 64 + col16;
    #pragma unroll
    for (int n = 0; n < 4; ++n) {
        int col = colb + n * 16;
        int h = col / 192;
        int rem = col - h * 192;
        int part = rem >> 6, d = rem & 63;   // wave-uniform
        float bv = bias[col];
        #pragma unroll
        for (int m = 0; m < 4; ++m) {
            int r0 = rowb + m * 16;
            int b = r0 >> 11, s0r = r0 & 2047;
            int bh = b * 16 + h;
            if (part == 0) {
                #pragma unroll
                for (int j = 0; j < 4; ++j)
                    Qf[((size_t)bh * 2048 + s0r + j) * 64 + d] =
                        (_Float16)((acc[m][n][j] + bv) * QSCALE);
            } else if (part == 1) {
                #pragma unroll
                for (int j = 0; j < 4; ++j)
                    Kf[((size_t)bh * 2048 + s0r + j) * 64 + d] = (_Float16)(acc[m][n][j] + bv);
            } else {
                half4 pk;
                pk[0] = (_Float16)(acc[m][n][0] + bv);
                pk[1] = (_Float16)(acc[m][n][1] + bv);
                pk[2] = (_Float16)(acc[m][n][2] + bv);
                pk[3] = (_Float16)(acc[m][n][3] + bv);
                *(half4*)&VfT[((size_t)bh * 64 + d) * 2048 + s0r] = pk;
            }
        }
    }
}

// MFMA flash attention, 32x32 f16, in-register P, absolute-score softmax,
// 2-TILE SOFTWARE PIPELINE: iter t computes QK(t) while softmax+PV run on tile t-1.
// K double-buffered, V triple-buffered (PV(t-1) read vs STAGE(t+1) write).
// 8 identical waves, q-tile 256; grid remapped so a head's 8 q-blocks share one XCD.
__global__ __launch_bounds__(512, 2) void mfma_attn(
    const _Float16* __restrict__ Qf, const _Float16* __restrict__ Kf,
    const _Float16* __restrict__ VfT, _Float16* __restrict__ vals) {
    __shared__ __align__(1024) unsigned char smem[40960];  // K0,K1 @0,8K; V0,V1,V2 @16K,24K,32K
    const int tid = threadIdx.x;
    const int l = tid & 63, w = tid >> 6;          // 8 waves
    const int l31 = l & 31, hl = l >> 5;
    const int hwbid = blockIdx.y * gridDim.x + blockIdx.x;
    const int q_t = (hwbid >> 3) & 7;
    const int bh = (hwbid & 7) + ((hwbid >> 6) << 3);
    const int q0 = q_t * 256;
    const int h = bh & 15, b = bh >> 4;

    half8 qf[4];
    {
        const _Float16* qp = Qf + ((size_t)bh * 2048 + q0 + w * 32 + l31) * 64 + hl * 8;
        #pragma unroll
        for (int c = 0; c < 4; ++c) qf[c] = *(const half8*)(qp + c * 16);
    }
    f32x16 zvec = {};
    f32x16 o0 = {}, o1 = {};
    float mshift = 0.f, lsum = 0.f;

    const _Float16* Kg = Kf + (size_t)bh * 2048 * 64;
    const _Float16* Vg = VfT + (size_t)bh * 64 * 2048;

    int offK, offV;
    {
        int row2 = w * 4 + (l >> 4);
        int slot = (l & 15) ^ (row2 & 15);
        int row = row2 * 2 + (slot >> 3);
        int chunk = slot & 7;
        offK = row * 64 + chunk * 8;
        offV = row * 2048 + chunk * 8;
    }
    const int sbase = (l31 & 1) * 8;
    const int xr = (l31 >> 1) & 15;
    const int rb0 = (l31 >> 1) * 256;

    #define STAGE(kt0, kbuf, vbuf)                                                     \
        {                                                                              \
            unsigned char* bK = smem + (kbuf) * 8192 + w * 1024;                       \
            unsigned char* bV = smem + 16384 + (vbuf) * 8192 + w * 1024;               \
            load_lds16(Kg + (size_t)(kt0) * 64 + offK, bK);                            \
            load_lds16(Vg + (kt0) + offV, bV);                                         \
        }

    #define QK_TILE(kb, D0, D1)                                                        \
        {                                                                              \
            const unsigned char* Ksb_ = smem + (kb) * 8192;                            \
            __builtin_amdgcn_s_setprio(1);                                             \
            {                                                                          \
                int chOff = ((sbase + hl) ^ xr) << 4;                                  \
                half8 k0_ = *(const half8*)(Ksb_ + rb0 + chOff);                       \
                half8 k1_ = *(const half8*)(Ksb_ + rb0 + 4096 + chOff);                \
                D0 = __builtin_amdgcn_mfma_f32_32x32x16_f16(k0_, qf[0], zvec, 0, 0, 0);\
                D1 = __builtin_amdgcn_mfma_f32_32x32x16_f16(k1_, qf[0], zvec, 0, 0, 0);\
            }                                                                          \
            _Pragma("unroll")                                                          \
            for (int kc = 1; kc < 4; ++kc) {                                           \
                int chOff = ((sbase + kc * 2 + hl) ^ xr) << 4;                         \
                half8 k0_ = *(const half8*)(Ksb_ + rb0 + chOff);                       \
                half8 k1_ = *(const half8*)(Ksb_ + rb0 + 4096 + chOff);                \
                D0 = __builtin_amdgcn_mfma_f32_32x32x16_f16(k0_, qf[kc], D0, 0, 0, 0); \
                D1 = __builtin_amdgcn_mfma_f32_32x32x16_f16(k1_, qf[kc], D1, 0, 0, 0); \
            }                                                                          \
            __builtin_amdgcn_s_setprio(0);                                             \
        }

    // softmax + PV on tile whose scores are in S0/S1; V buffer index = vrd
    #define SMPV(S0, S1)                                                               \
        {                                                                              \
            const unsigned char* Vsb_ = smem + 16384 + vrd * 8192;                     \
            if (__any(mshift != 0.f)) {                                                \
                _Pragma("unroll")                                                      \
                for (int r = 0; r < 16; ++r) { S0[r] -= mshift; S1[r] -= mshift; }     \
            }                                                                          \
            float r0 = 0.f, r1 = 0.f, r2 = 0.f, r3 = 0.f;                              \
            unsigned int a[2][8];                                                      \
            _Pragma("unroll")                                                          \
            for (int j = 0; j < 8; ++j) {                                              \
                float p0 = __builtin_amdgcn_exp2f(S0[2 * j]);                          \
                float p1 = __builtin_amdgcn_exp2f(S0[2 * j + 1]);                      \
                float q0_ = __builtin_amdgcn_exp2f(S1[2 * j]);                         \
                float q1_ = __builtin_amdgcn_exp2f(S1[2 * j + 1]);                     \
                r0 += p0; r1 += p1; r2 += q0_; r3 += q1_;                              \
                a[0][j] = __builtin_bit_cast(unsigned int, __builtin_amdgcn_cvt_pkrtz(p0, p1));   \
                a[1][j] = __builtin_bit_cast(unsigned int, __builtin_amdgcn_cvt_pkrtz(q0_, q1_)); \
            }                                                                          \
            float rsum = (r0 + r1) + (r2 + r3);                                        \
            if (__any(rsum > 32768.f)) {                                               \
                float pmax = S0[0];                                                    \
                _Pragma("unroll")                                                      \
                for (int r = 1; r < 16; ++r) pmax = fmaxf(pmax, S0[r]);                \
                _Pragma("unroll")                                                      \
                for (int r = 0; r < 16; ++r) pmax = fmaxf(pmax, S1[r]);                \
                pmax = fmaxf(pmax, __shfl_xor(pmax, 32, 64));                          \
                float d_ = fmaxf(pmax, 0.f);                                           \
                float corr = __builtin_amdgcn_exp2f(-d_);                              \
                _Pragma("unroll")                                                      \
                for (int r = 0; r < 16; ++r) { S0[r] -= d_; S1[r] -= d_; }             \
                _Pragma("unroll")                                                      \
                for (int r = 0; r < 16; ++r) { o0[r] *= corr; o1[r] *= corr; }         \
                lsum *= corr;                                                          \
                mshift += d_;                                                          \
                r0 = r1 = r2 = r3 = 0.f;                                               \
                _Pragma("unroll")                                                      \
                for (int j = 0; j < 8; ++j) {                                          \
                    float p0 = __builtin_amdgcn_exp2f(S0[2 * j]);                      \
                    float p1 = __builtin_amdgcn_exp2f(S0[2 * j + 1]);                  \
                    float q0_ = __builtin_amdgcn_exp2f(S1[2 * j]);                     \
                    float q1_ = __builtin_amdgcn_exp2f(S1[2 * j + 1]);                 \
                    r0 += p0; r1 += p1; r2 += q0_; r3 += q1_;                          \
                    a[0][j] = __builtin_bit_cast(unsigned int, __builtin_amdgcn_cvt_pkrtz(p0, p1));   \
                    a[1][j] = __builtin_bit_cast(unsigned int, __builtin_amdgcn_cvt_pkrtz(q0_, q1_)); \
                }                                                                      \
                rsum = (r0 + r1) + (r2 + r3);                                          \
            }                                                                          \
            lsum += rsum;                                                              \
            _Pragma("unroll")                                                          \
            for (int c = 0; c < 2; ++c) {                                              \
                pl32swap(a[c][0], a[c][2]);                                            \
                pl32swap(a[c][1], a[c][3]);                                            \
                pl32swap(a[c][4], a[c][6]);                                            \
                pl32swap(a[c][5], a[c][7]);                                            \
            }                                                                          \
            __builtin_amdgcn_s_setprio(1);                                             \
            _Pragma("unroll")                                                          \
            for (int kk = 0; kk < 4; ++kk) {                                           \
                u32x4 pw;                                                              \
                pw.x = a[kk >> 1][(kk & 1) * 4 + 0];                                   \
                pw.y = a[kk >> 1][(kk & 1) * 4 + 1];                                   \
                pw.z = a[kk >> 1][(kk & 1) * 4 + 2];                                   \
                pw.w = a[kk >> 1][(kk & 1) * 4 + 3];                                   \
                half8 pf = __builtin_bit_cast(half8, pw);                              \
                int chOff = ((sbase + kk * 2 + hl) ^ xr) << 4;                         \
                half8 v0 = *(const half8*)(Vsb_ + rb0 + chOff);                        \
                half8 v1 = *(const half8*)(Vsb_ + rb0 + 4096 + chOff);                 \
                o0 = __builtin_amdgcn_mfma_f32_32x32x16_f16(v0, pf, o0, 0, 0, 0);      \
                o1 = __builtin_amdgcn_mfma_f32_32x32x16_f16(v1, pf, o1, 0, 0, 0);      \
            }                                                                          \
            __builtin_amdgcn_s_setprio(0);                                             \
        }

    // iter t: barrier; STAGE(t+1); QK(t)->DST; softmax+PV(prev) with V[vrd]
    #define ITER(tt, kb, D0, D1, P0, P1, dostage)                                      \
        __syncthreads();                                                               \
        if (dostage) STAGE(((tt) + 1) * 64, (kb) ^ 1, vst)                             \
        QK_TILE(kb, D0, D1)                                                            \
        SMPV(P0, P1)                                                                   \
        vrd = (vrd == 2) ? 0 : vrd + 1;                                                \
        vst = (vst == 2) ? 0 : vst + 1;

    int vrd = 0, vst = 2;
    f32x16 sA0, sA1, sB0, sB1;

    STAGE(0, 0, 0)
    __syncthreads();
    QK_TILE(0, sA0, sA1)
    STAGE(64, 1, 1)

    for (int t = 1; t < 31; t += 2) {
        ITER(t, 1, sB0, sB1, sA0, sA1, 1)
        ITER(t + 1, 0, sA0, sA1, sB0, sB1, 1)
    }
    ITER(31, 1, sB0, sB1, sA0, sA1, 0)
    SMPV(sB0, sB1)   // tile 31, V[vrd]

    // ---- epilogue ----
    lsum += __shfl_xor(lsum, 32, 64);
    float inv = 1.f / lsum;
    size_t orow = ((size_t)(b * 2048 + q0 + w * 32 + l31)) * 1024 + h * 64;
    #pragma unroll
    for (int dc = 0; dc < 2; ++dc) {
        const f32x16* op = dc ? &o1 : &o0;
        #pragma unroll
        for (int rq = 0; rq < 4; ++rq) {
            int d0 = dc * 32 + rq * 8 + hl * 4;
            half4 hv;
            #pragma unroll
            for (int j = 0; j < 4; ++j) hv[j] = (_Float16)((*op)[rq * 4 + j] * inv);
            *(half4*)(vals + orow + d0) = hv;
        }
    }
}

extern "C" void kernel_launch(void* const* d_in, const int* in_sizes, int n_in,
                              void* d_out, int out_size, void* d_ws, size_t ws_size,
                              hipStream_t stream) {
    const float* x     = (const float*)d_in[0];
    const float* w_qkv = (const float*)d_in[1];
    const float* b_qkv = (const float*)d_in[2];
    const float* w_o   = (const float*)d_in[3];
    const float* b_o   = (const float*)d_in[4];
    float* out = (float*)d_out;

    const int B = 2, S = 2048, D = 1024;
    const int M = B * S;          // 4096
    const int N1 = 3 * D;         // 3072
    const int BH = B * NHEADS;    // 32

    _Float16* xf  = (_Float16*)d_ws;                  // [4096,1024]
    _Float16* wqf = xf  + (size_t)M * D;              // [3072,1024]
    _Float16* wof = wqf + (size_t)N1 * D;             // [1024,1024]
    _Float16* Qf  = wof + (size_t)D * D;              // [32,2048,64]
    _Float16* Kf  = Qf  + (size_t)BH * S * HD;
    _Float16* VfT = Kf  + (size_t)BH * S * HD;        // [32,64,2048]
    _Float16* vals = xf;   // reuse x-f16 space after gemm_qkv

    // 0) all f32->f16 conversions in one launch
    cvt_all<<<(NX + NWQ + NWO) / 2048, 256, 0, stream>>>(x, w_qkv, w_o, xf, wqf, wof);

    // 1) fused QKV projection -> f16 attention layouts
    gemm_qkv<<<dim3(N1 / 128, M / 128), 256, 0, stream>>>(xf, wqf, b_qkv, Qf, Kf, VfT, D);

    // 2) MFMA flash attention (32x32 f16, 2-tile pipelined, XCD-grouped)
    mfma_attn<<<dim3(S / 256, BH), 512, 0, stream>>>(Qf, Kf, VfT, vals);

    // 3) out = vals @ w_o^T + b_o
    gemm_o<<<dim3(D / 128, M / 128), 256, 0, stream>>>(vals, wof, b_o, out, M, D, D);
}

// Round 13
// 109.496 us; speedup vs baseline: 1.1580x; 1.0310x over previous
//
#include <hip/hip_runtime.h>
#include <math.h>

#define NHEADS 16
#define HD 64

typedef __attribute__((ext_vector_type(8))) _Float16 half8;
typedef __attribute__((ext_vector_type(4))) _Float16 half4;
typedef __attribute__((ext_vector_type(4))) float f32x4;
typedef __attribute__((ext_vector_type(16))) float f32x16;
typedef __attribute__((ext_vector_type(4))) unsigned int u32x4;

__device__ inline void load_lds16(const void* g, void* l) {
    __builtin_amdgcn_global_load_lds(
        (const __attribute__((address_space(1))) unsigned int*)g,
        (__attribute__((address_space(3))) unsigned int*)l, 16, 0, 0);
}
__device__ inline void pl32swap(unsigned int& x, unsigned int& y) {
    asm volatile("v_permlane32_swap_b32 %0, %1" : "+v"(x), "+v"(y));
}

// fp32 -> fp16 for x, w_qkv, w_o in ONE launch. Segment by flat index.
#define NX  4194304   // 4096*1024
#define NWQ 3145728   // 3072*1024
#define NWO 1048576   // 1024*1024
__global__ void cvt_all(const float* __restrict__ x, const float* __restrict__ wq,
                        const float* __restrict__ wo, _Float16* __restrict__ xf,
                        _Float16* __restrict__ wqf, _Float16* __restrict__ wof) {
    int i = (blockIdx.x * blockDim.x + threadIdx.x) * 8;
    const float* src; _Float16* dst; int off;
    if (i < NX)            { src = x;  dst = xf;  off = i; }
    else if (i < NX + NWQ) { src = wq; dst = wqf; off = i - NX; }
    else                   { src = wo; dst = wof; off = i - (NX + NWQ); }
    float4 a = *(const float4*)(src + off);
    float4 b = *(const float4*)(src + off + 4);
    half8 h;
    h[0] = (_Float16)a.x; h[1] = (_Float16)a.y; h[2] = (_Float16)a.z; h[3] = (_Float16)a.w;
    h[4] = (_Float16)b.x; h[5] = (_Float16)b.y; h[6] = (_Float16)b.z; h[7] = (_Float16)b.w;
    *(half8*)(dst + off) = h;
}

// ---- 128x128 GEMM core (used by gemm_qkv): BK=32, f16 MFMA, XCD-swizzled ----
#define GEMM_CORE(K)                                                                   \
    __shared__ __align__(1024) unsigned char smem[16384];                              \
    const int tid = threadIdx.x;                                                       \
    const int l = tid & 63, w = tid >> 6;                                              \
    const int wr = w >> 1, wc = w & 1;                                                 \
    const int nwg = gridDim.x * gridDim.y;                                             \
    const int bid = blockIdx.y * gridDim.x + blockIdx.x;                               \
    const int swz = (bid & 7) * (nwg >> 3) + (bid >> 3);                               \
    const int m0 = (swz / gridDim.x) * 128, n0 = (swz % gridDim.x) * 128;              \
    const int srow = tid >> 2;                                                         \
    const int schunk = (tid & 3) ^ ((srow >> 1) & 3);                                  \
    const size_t gA0 = (size_t)(m0 + srow) * K + schunk * 8;                           \
    const size_t gA1 = gA0 + (size_t)64 * K;                                           \
    const size_t gB0 = (size_t)(n0 + srow) * K + schunk * 8;                           \
    const size_t gB1 = gB0 + (size_t)64 * K;                                           \
    unsigned char* ldsW = smem + w * 1024;                                             \
    const int col16 = l & 15, kc = l >> 4;                                             \
    const int ra0 = wr * 64 + col16;                                                   \
    const int offA = ra0 * 64 + ((kc ^ ((ra0 >> 1) & 3)) * 16);                        \
    const int rb0 = wc * 64 + col16;                                                   \
    const int offB = rb0 * 64 + ((kc ^ ((rb0 >> 1) & 3)) * 16);                        \
    f32x4 acc[4][4] = {};                                                              \
    for (int k0 = 0; k0 < K; k0 += 32) {                                               \
        load_lds16(A + gA0 + k0, ldsW + 0);                                            \
        load_lds16(A + gA1 + k0, ldsW + 4096);                                         \
        load_lds16(B + gB0 + k0, ldsW + 8192);                                         \
        load_lds16(B + gB1 + k0, ldsW + 12288);                                       \
        __syncthreads();                                                               \
        half8 af[4], bf[4];                                                            \
        _Pragma("unroll")                                                              \
        for (int m = 0; m < 4; ++m) af[m] = *(const half8*)(smem + offA + m * 1024);   \
        _Pragma("unroll")                                                              \
        for (int n = 0; n < 4; ++n) bf[n] = *(const half8*)(smem + 8192 + offB + n * 1024); \
        _Pragma("unroll")                                                              \
        for (int m = 0; m < 4; ++m)                                                    \
            _Pragma("unroll")                                                          \
            for (int n = 0; n < 4; ++n)                                                \
                acc[m][n] = __builtin_amdgcn_mfma_f32_16x16x32_f16(af[m], bf[n], acc[m][n], 0, 0, 0); \
        __syncthreads();                                                               \
    }

// out[M,N] = A[M,K] @ B[N,K]^T + bias, f32 out. 128x64 tile (512 blocks -> 2/CU).
__global__ __launch_bounds__(256, 2) void gemm_o(
    const _Float16* __restrict__ A, const _Float16* __restrict__ B,
    const float* __restrict__ bias, float* __restrict__ C,
    int M, int N, int K) {
    __shared__ __align__(1024) unsigned char smem[12288];  // A[128][32] @0, B[64][32] @8192
    const int tid = threadIdx.x;
    const int l = tid & 63, w = tid >> 6;
    const int wr = w >> 1, wc = w & 1;
    const int nwg = gridDim.x * gridDim.y;
    const int bid = blockIdx.y * gridDim.x + blockIdx.x;
    const int swz = (bid & 7) * (nwg >> 3) + (bid >> 3);
    const int m0 = (swz / gridDim.x) * 128, n0 = (swz % gridDim.x) * 64;
    const int srow = tid >> 2;
    const int schunk = (tid & 3) ^ ((srow >> 1) & 3);
    const size_t gA0 = (size_t)(m0 + srow) * K + schunk * 8;
    const size_t gA1 = gA0 + (size_t)64 * K;
    const size_t gB0 = (size_t)(n0 + srow) * K + schunk * 8;
    unsigned char* ldsW = smem + w * 1024;
    const int col16 = l & 15, kc = l >> 4;
    const int ra0 = wr * 64 + col16;
    const int offA = ra0 * 64 + ((kc ^ ((ra0 >> 1) & 3)) * 16);
    const int rb0 = wc * 32 + col16;
    const int offB = 8192 + rb0 * 64 + ((kc ^ ((rb0 >> 1) & 3)) * 16);
    f32x4 acc[4][2] = {};
    for (int k0 = 0; k0 < K; k0 += 32) {
        load_lds16(A + gA0 + k0, ldsW + 0);
        load_lds16(A + gA1 + k0, ldsW + 4096);
        load_lds16(B + gB0 + k0, ldsW + 8192);
        __syncthreads();
        half8 af[4], bf[2];
        #pragma unroll
        for (int m = 0; m < 4; ++m) af[m] = *(const half8*)(smem + offA + m * 1024);
        #pragma unroll
        for (int n = 0; n < 2; ++n) bf[n] = *(const half8*)(smem + offB + n * 1024);
        #pragma unroll
        for (int m = 0; m < 4; ++m)
            #pragma unroll
            for (int n = 0; n < 2; ++n)
                acc[m][n] = __builtin_amdgcn_mfma_f32_16x16x32_f16(af[m], bf[n], acc[m][n], 0, 0, 0);
        __syncthreads();
    }
    const int rowb = m0 + wr * 64 + (l >> 4) * 4;
    const int colb = n0 + wc * 32 + col16;
    float bv[2];
    #pragma unroll
    for (int n = 0; n < 2; ++n) bv[n] = bias[colb + n * 16];
    #pragma unroll
    for (int m = 0; m < 4; ++m)
        #pragma unroll
        for (int j = 0; j < 4; ++j) {
            float* crow = C + (size_t)(rowb + m * 16 + j) * N + colb;
            #pragma unroll
            for (int n = 0; n < 2; ++n) crow[n * 16] = acc[m][n][j] + bv[n];
        }
}

// QKV GEMM, fused epilogue -> Qf (scaled 0.125*log2e) / Kf [bh][s][64], VfT [bh][d][s]
#define QSCALE 0.18033688f
__global__ __launch_bounds__(256, 2) void gemm_qkv(
    const _Float16* __restrict__ A, const _Float16* __restrict__ B,
    const float* __restrict__ bias,
    _Float16* __restrict__ Qf, _Float16* __restrict__ Kf,
    _Float16* __restrict__ VfT, int K) {
    GEMM_CORE(K)
    const int rowb = m0 + wr * 64 + (l >> 4) * 4;
    const int colb = n0 + wc * 64 + col16;
    #pragma unroll
    for (int n = 0; n < 4; ++n) {
        int col = colb + n * 16;
        int h = col / 192;
        int rem = col - h * 192;
        int part = rem >> 6, d = rem & 63;   // wave-uniform
        float bv = bias[col];
        #pragma unroll
        for (int m = 0; m < 4; ++m) {
            int r0 = rowb + m * 16;
            int b = r0 >> 11, s0r = r0 & 2047;
            int bh = b * 16 + h;
            if (part == 0) {
                #pragma unroll
                for (int j = 0; j < 4; ++j)
                    Qf[((size_t)bh * 2048 + s0r + j) * 64 + d] =
                        (_Float16)((acc[m][n][j] + bv) * QSCALE);
            } else if (part == 1) {
                #pragma unroll
                for (int j = 0; j < 4; ++j)
                    Kf[((size_t)bh * 2048 + s0r + j) * 64 + d] = (_Float16)(acc[m][n][j] + bv);
            } else {
                half4 pk;
                pk[0] = (_Float16)(acc[m][n][0] + bv);
                pk[1] = (_Float16)(acc[m][n][1] + bv);
                pk[2] = (_Float16)(acc[m][n][2] + bv);
                pk[3] = (_Float16)(acc[m][n][3] + bv);
                *(half4*)&VfT[((size_t)bh * 64 + d) * 2048 + s0r] = pk;
            }
        }
    }
}

// MFMA flash attention, 32x32 f16, in-register P, absolute-score softmax,
// 2-tile pipeline, NO setprio fences (A/B test: let the compiler blend phases).
__global__ __launch_bounds__(512, 2) void mfma_attn(
    const _Float16* __restrict__ Qf, const _Float16* __restrict__ Kf,
    const _Float16* __restrict__ VfT, _Float16* __restrict__ vals) {
    __shared__ __align__(1024) unsigned char smem[40960];  // K0,K1 @0,8K; V0,V1,V2 @16K,24K,32K
    const int tid = threadIdx.x;
    const int l = tid & 63, w = tid >> 6;          // 8 waves
    const int l31 = l & 31, hl = l >> 5;
    const int hwbid = blockIdx.y * gridDim.x + blockIdx.x;
    const int q_t = (hwbid >> 3) & 7;
    const int bh = (hwbid & 7) + ((hwbid >> 6) << 3);
    const int q0 = q_t * 256;
    const int h = bh & 15, b = bh >> 4;

    half8 qf[4];
    {
        const _Float16* qp = Qf + ((size_t)bh * 2048 + q0 + w * 32 + l31) * 64 + hl * 8;
        #pragma unroll
        for (int c = 0; c < 4; ++c) qf[c] = *(const half8*)(qp + c * 16);
    }
    f32x16 zvec = {};
    f32x16 o0 = {}, o1 = {};
    float mshift = 0.f, lsum = 0.f;

    const _Float16* Kg = Kf + (size_t)bh * 2048 * 64;
    const _Float16* Vg = VfT + (size_t)bh * 64 * 2048;

    int offK, offV;
    {
        int row2 = w * 4 + (l >> 4);
        int slot = (l & 15) ^ (row2 & 15);
        int row = row2 * 2 + (slot >> 3);
        int chunk = slot & 7;
        offK = row * 64 + chunk * 8;
        offV = row * 2048 + chunk * 8;
    }
    const int sbase = (l31 & 1) * 8;
    const int xr = (l31 >> 1) & 15;
    const int rb0 = (l31 >> 1) * 256;

    #define STAGE(kt0, kbuf, vbuf)                                                     \
        {                                                                              \
            unsigned char* bK = smem + (kbuf) * 8192 + w * 1024;                       \
            unsigned char* bV = smem + 16384 + (vbuf) * 8192 + w * 1024;               \
            load_lds16(Kg + (size_t)(kt0) * 64 + offK, bK);                            \
            load_lds16(Vg + (kt0) + offV, bV);                                         \
        }

    #define QK_TILE(kb, D0, D1)                                                        \
        {                                                                              \
            const unsigned char* Ksb_ = smem + (kb) * 8192;                            \
            {                                                                          \
                int chOff = ((sbase + hl) ^ xr) << 4;                                  \
                half8 k0_ = *(const half8*)(Ksb_ + rb0 + chOff);                       \
                half8 k1_ = *(const half8*)(Ksb_ + rb0 + 4096 + chOff);                \
                D0 = __builtin_amdgcn_mfma_f32_32x32x16_f16(k0_, qf[0], zvec, 0, 0, 0);\
                D1 = __builtin_amdgcn_mfma_f32_32x32x16_f16(k1_, qf[0], zvec, 0, 0, 0);\
            }                                                                          \
            _Pragma("unroll")                                                          \
            for (int kc = 1; kc < 4; ++kc) {                                           \
                int chOff = ((sbase + kc * 2 + hl) ^ xr) << 4;                         \
                half8 k0_ = *(const half8*)(Ksb_ + rb0 + chOff);                       \
                half8 k1_ = *(const half8*)(Ksb_ + rb0 + 4096 + chOff);                \
                D0 = __builtin_amdgcn_mfma_f32_32x32x16_f16(k0_, qf[kc], D0, 0, 0, 0); \
                D1 = __builtin_amdgcn_mfma_f32_32x32x16_f16(k1_, qf[kc], D1, 0, 0, 0); \
            }                                                                          \
        }

    // softmax + PV on tile whose scores are in S0/S1; V buffer index = vrd
    #define SMPV(S0, S1)                                                               \
        {                                                                              \
            const unsigned char* Vsb_ = smem + 16384 + vrd * 8192;                     \
            if (__any(mshift != 0.f)) {                                                \
                _Pragma("unroll")                                                      \
                for (int r = 0; r < 16; ++r) { S0[r] -= mshift; S1[r] -= mshift; }     \
            }                                                                          \
            float r0 = 0.f, r1 = 0.f, r2 = 0.f, r3 = 0.f;                              \
            unsigned int a[2][8];                                                      \
            _Pragma("unroll")                                                          \
            for (int j = 0; j < 8; ++j) {                                              \
                float p0 = __builtin_amdgcn_exp2f(S0[2 * j]);                          \
                float p1 = __builtin_amdgcn_exp2f(S0[2 * j + 1]);                      \
                float q0_ = __builtin_amdgcn_exp2f(S1[2 * j]);                         \
                float q1_ = __builtin_amdgcn_exp2f(S1[2 * j + 1]);                     \
                r0 += p0; r1 += p1; r2 += q0_; r3 += q1_;                              \
                a[0][j] = __builtin_bit_cast(unsigned int, __builtin_amdgcn_cvt_pkrtz(p0, p1));   \
                a[1][j] = __builtin_bit_cast(unsigned int, __builtin_amdgcn_cvt_pkrtz(q0_, q1_)); \
            }                                                                          \
            float rsum = (r0 + r1) + (r2 + r3);                                        \
            if (__any(rsum > 32768.f)) {                                               \
                float pmax = S0[0];                                                    \
                _Pragma("unroll")                                                      \
                for (int r = 1; r < 16; ++r) pmax = fmaxf(pmax, S0[r]);                \
                _Pragma("unroll")                                                      \
                for (int r = 0; r < 16; ++r) pmax = fmaxf(pmax, S1[r]);                \
                pmax = fmaxf(pmax, __shfl_xor(pmax, 32, 64));                          \
                float d_ = fmaxf(pmax, 0.f);                                           \
                float corr = __builtin_amdgcn_exp2f(-d_);                              \
                _Pragma("unroll")                                                      \
                for (int r = 0; r < 16; ++r) { S0[r] -= d_; S1[r] -= d_; }             \
                _Pragma("unroll")                                                      \
                for (int r = 0; r < 16; ++r) { o0[r] *= corr; o1[r] *= corr; }         \
                lsum *= corr;                                                          \
                mshift += d_;                                                          \
                r0 = r1 = r2 = r3 = 0.f;                                               \
                _Pragma("unroll")                                                      \
                for (int j = 0; j < 8; ++j) {                                          \
                    float p0 = __builtin_amdgcn_exp2f(S0[2 * j]);                      \
                    float p1 = __builtin_amdgcn_exp2f(S0[2 * j + 1]);                  \
                    float q0_ = __builtin_amdgcn_exp2f(S1[2 * j]);                     \
                    float q1_ = __builtin_amdgcn_exp2f(S1[2 * j + 1]);                 \
                    r0 += p0; r1 += p1; r2 += q0_; r3 += q1_;                          \
                    a[0][j] = __builtin_bit_cast(unsigned int, __builtin_amdgcn_cvt_pkrtz(p0, p1));   \
                    a[1][j] = __builtin_bit_cast(unsigned int, __builtin_amdgcn_cvt_pkrtz(q0_, q1_)); \
                }                                                                      \
                rsum = (r0 + r1) + (r2 + r3);                                          \
            }                                                                          \
            lsum += rsum;                                                              \
            _Pragma("unroll")                                                          \
            for (int c = 0; c < 2; ++c) {                                              \
                pl32swap(a[c][0], a[c][2]);                                            \
                pl32swap(a[c][1], a[c][3]);                                            \
                pl32swap(a[c][4], a[c][6]);                                            \
                pl32swap(a[c][5], a[c][7]);                                            \
            }                                                                          \
            _Pragma("unroll")                                                          \
            for (int kk = 0; kk < 4; ++kk) {                                           \
                u32x4 pw;                                                              \
                pw.x = a[kk >> 1][(kk & 1) * 4 + 0];                                   \
                pw.y = a[kk >> 1][(kk & 1) * 4 + 1];                                   \
                pw.z = a[kk >> 1][(kk & 1) * 4 + 2];                                   \
                pw.w = a[kk >> 1][(kk & 1) * 4 + 3];                                   \
                half8 pf = __builtin_bit_cast(half8, pw);                              \
                int chOff = ((sbase + kk * 2 + hl) ^ xr) << 4;                         \
                half8 v0 = *(const half8*)(Vsb_ + rb0 + chOff);                        \
                half8 v1 = *(const half8*)(Vsb_ + rb0 + 4096 + chOff);                 \
                o0 = __builtin_amdgcn_mfma_f32_32x32x16_f16(v0, pf, o0, 0, 0, 0);      \
                o1 = __builtin_amdgcn_mfma_f32_32x32x16_f16(v1, pf, o1, 0, 0, 0);      \
            }                                                                          \
        }

    // iter t: barrier; STAGE(t+1); QK(t)->DST; softmax+PV(prev) with V[vrd]
    #define ITER(tt, kb, D0, D1, P0, P1, dostage)                                      \
        __syncthreads();                                                               \
        if (dostage) STAGE(((tt) + 1) * 64, (kb) ^ 1, vst)                             \
        QK_TILE(kb, D0, D1)                                                            \
        SMPV(P0, P1)                                                                   \
        vrd = (vrd == 2) ? 0 : vrd + 1;                                                \
        vst = (vst == 2) ? 0 : vst + 1;

    int vrd = 0, vst = 2;
    f32x16 sA0, sA1, sB0, sB1;

    STAGE(0, 0, 0)
    __syncthreads();
    QK_TILE(0, sA0, sA1)
    STAGE(64, 1, 1)

    for (int t = 1; t < 31; t += 2) {
        ITER(t, 1, sB0, sB1, sA0, sA1, 1)
        ITER(t + 1, 0, sA0, sA1, sB0, sB1, 1)
    }
    ITER(31, 1, sB0, sB1, sA0, sA1, 0)
    SMPV(sB0, sB1)   // tile 31, V[vrd]

    // ---- epilogue ----
    lsum += __shfl_xor(lsum, 32, 64);
    float inv = 1.f / lsum;
    size_t orow = ((size_t)(b * 2048 + q0 + w * 32 + l31)) * 1024 + h * 64;
    #pragma unroll
    for (int dc = 0; dc < 2; ++dc) {
        const f32x16* op = dc ? &o1 : &o0;
        #pragma unroll
        for (int rq = 0; rq < 4; ++rq) {
            int d0 = dc * 32 + rq * 8 + hl * 4;
            half4 hv;
            #pragma unroll
            for (int j = 0; j < 4; ++j) hv[j] = (_Float16)((*op)[rq * 4 + j] * inv);
            *(half4*)(vals + orow + d0) = hv;
        }
    }
}

extern "C" void kernel_launch(void* const* d_in, const int* in_sizes, int n_in,
                              void* d_out, int out_size, void* d_ws, size_t ws_size,
                              hipStream_t stream) {
    const float* x     = (const float*)d_in[0];
    const float* w_qkv = (const float*)d_in[1];
    const float* b_qkv = (const float*)d_in[2];
    const float* w_o   = (const float*)d_in[3];
    const float* b_o   = (const float*)d_in[4];
    float* out = (float*)d_out;

    const int B = 2, S = 2048, D = 1024;
    const int M = B * S;          // 4096
    const int N1 = 3 * D;         // 3072
    const int BH = B * NHEADS;    // 32

    _Float16* xf  = (_Float16*)d_ws;                  // [4096,1024]
    _Float16* wqf = xf  + (size_t)M * D;              // [3072,1024]
    _Float16* wof = wqf + (size_t)N1 * D;             // [1024,1024]
    _Float16* Qf  = wof + (size_t)D * D;              // [32,2048,64]
    _Float16* Kf  = Qf  + (size_t)BH * S * HD;
    _Float16* VfT = Kf  + (size_t)BH * S * HD;        // [32,64,2048]
    _Float16* vals = xf;   // reuse x-f16 space after gemm_qkv

    // 0) all f32->f16 conversions in one launch
    cvt_all<<<(NX + NWQ + NWO) / 2048, 256, 0, stream>>>(x, w_qkv, w_o, xf, wqf, wof);

    // 1) fused QKV projection -> f16 attention layouts
    gemm_qkv<<<dim3(N1 / 128, M / 128), 256, 0, stream>>>(xf, wqf, b_qkv, Qf, Kf, VfT, D);

    // 2) MFMA flash attention (32x32 f16, 2-tile pipelined, no setprio)
    mfma_attn<<<dim3(S / 256, BH), 512, 0, stream>>>(Qf, Kf, VfT, vals);

    // 3) out = vals @ w_o^T + b_o  (128x64 tile, 512 blocks)
    gemm_o<<<dim3(D / 64, M / 128), 256, 0, stream>>>(vals, wof, b_o, out, M, D, D);
}

// Round 14
// 107.230 us; speedup vs baseline: 1.1825x; 1.0211x over previous
//
#include <hip/hip_runtime.h>
#include <math.h>

#define NHEADS 16
#define HD 64

typedef __attribute__((ext_vector_type(8))) _Float16 half8;
typedef __attribute__((ext_vector_type(4))) _Float16 half4;
typedef __attribute__((ext_vector_type(4))) float f32x4;
typedef __attribute__((ext_vector_type(16))) float f32x16;
typedef __attribute__((ext_vector_type(4))) unsigned int u32x4;

__device__ inline void load_lds16(const void* g, void* l) {
    __builtin_amdgcn_global_load_lds(
        (const __attribute__((address_space(1))) unsigned int*)g,
        (__attribute__((address_space(3))) unsigned int*)l, 16, 0, 0);
}
__device__ inline void pl32swap(unsigned int& x, unsigned int& y) {
    asm volatile("v_permlane32_swap_b32 %0, %1" : "+v"(x), "+v"(y));
}

// fp32 -> fp16 for x, w_qkv, w_o in ONE launch. Segment by flat index.
#define NX  4194304   // 4096*1024
#define NWQ 3145728   // 3072*1024
#define NWO 1048576   // 1024*1024
__global__ void cvt_all(const float* __restrict__ x, const float* __restrict__ wq,
                        const float* __restrict__ wo, _Float16* __restrict__ xf,
                        _Float16* __restrict__ wqf, _Float16* __restrict__ wof) {
    int i = (blockIdx.x * blockDim.x + threadIdx.x) * 8;
    const float* src; _Float16* dst; int off;
    if (i < NX)            { src = x;  dst = xf;  off = i; }
    else if (i < NX + NWQ) { src = wq; dst = wqf; off = i - NX; }
    else                   { src = wo; dst = wof; off = i - (NX + NWQ); }
    float4 a = *(const float4*)(src + off);
    float4 b = *(const float4*)(src + off + 4);
    half8 h;
    h[0] = (_Float16)a.x; h[1] = (_Float16)a.y; h[2] = (_Float16)a.z; h[3] = (_Float16)a.w;
    h[4] = (_Float16)b.x; h[5] = (_Float16)b.y; h[6] = (_Float16)b.z; h[7] = (_Float16)b.w;
    *(half8*)(dst + off) = h;
}

// ---- common GEMM prologue (index math), 128-row A, parameterizable N-tile ----
#define GEMM_SETUP(K, NTILE)                                                           \
    const int tid = threadIdx.x;                                                       \
    const int l = tid & 63, w = tid >> 6;                                              \
    const int wr = w >> 1, wc = w & 1;                                                 \
    const int nwg = gridDim.x * gridDim.y;                                             \
    const int bid = blockIdx.y * gridDim.x + blockIdx.x;                               \
    const int swz = (bid & 7) * (nwg >> 3) + (bid >> 3);                               \
    const int m0 = (swz / gridDim.x) * 128, n0 = (swz % gridDim.x) * (NTILE);          \
    const int srow = tid >> 2;                                                         \
    const int schunk = (tid & 3) ^ ((srow >> 1) & 3);                                  \
    const size_t gA0 = (size_t)(m0 + srow) * K + schunk * 8;                           \
    const size_t gA1 = gA0 + (size_t)64 * K;                                           \
    const size_t gB0 = (size_t)(n0 + srow) * K + schunk * 8;                           \
    unsigned char* ldsW = smem + w * 1024;                                             \
    const int col16 = l & 15, kc = l >> 4;                                             \
    const int ra0 = wr * 64 + col16;                                                   \
    const int offA = ra0 * 64 + ((kc ^ ((ra0 >> 1) & 3)) * 16);

// QKV GEMM: 128x128 tile, K=1024 (32 steps), 3-buffer counted-vmcnt pipeline.
#define QSCALE 0.18033688f
__global__ __launch_bounds__(256, 2) void gemm_qkv(
    const _Float16* __restrict__ A, const _Float16* __restrict__ B,
    const float* __restrict__ bias,
    _Float16* __restrict__ Qf, _Float16* __restrict__ Kf,
    _Float16* __restrict__ VfT, int K) {
    __shared__ __align__(1024) unsigned char smem[49152];  // 3 x (A 8K + B 8K)
    GEMM_SETUP(K, 128)
    const size_t gB1 = gB0 + (size_t)64 * K;
    const int rb0 = wc * 64 + col16;
    const int offB = rb0 * 64 + ((kc ^ ((rb0 >> 1) & 3)) * 16);
    f32x4 acc[4][4] = {};

#define GSTAGE(k0_, buf_)                                                              \
    load_lds16(A + gA0 + (k0_), ldsW + (buf_) * 16384 + 0);                            \
    load_lds16(A + gA1 + (k0_), ldsW + (buf_) * 16384 + 4096);                         \
    load_lds16(B + gB0 + (k0_), ldsW + (buf_) * 16384 + 8192);                         \
    load_lds16(B + gB1 + (k0_), ldsW + (buf_) * 16384 + 12288);
#define GSTEP(s_, buf_, VM, dostage)                                                   \
    asm volatile("s_waitcnt " VM ::: "memory");                                        \
    __builtin_amdgcn_sched_barrier(0);                                                 \
    __builtin_amdgcn_s_barrier();                                                      \
    if (dostage) { GSTAGE(((s_) + 2) * 32, ((buf_) + 2) % 3) }                         \
    {                                                                                  \
        const unsigned char* bs = smem + (buf_) * 16384;                               \
        half8 af[4], bf[4];                                                            \
        _Pragma("unroll")                                                              \
        for (int m = 0; m < 4; ++m) af[m] = *(const half8*)(bs + offA + m * 1024);     \
        _Pragma("unroll")                                                              \
        for (int n = 0; n < 4; ++n) bf[n] = *(const half8*)(bs + 8192 + offB + n * 1024); \
        _Pragma("unroll")                                                              \
        for (int m = 0; m < 4; ++m)                                                    \
            _Pragma("unroll")                                                          \
            for (int n = 0; n < 4; ++n)                                                \
                acc[m][n] = __builtin_amdgcn_mfma_f32_16x16x32_f16(af[m], bf[n], acc[m][n], 0, 0, 0); \
    }

    GSTAGE(0, 0)
    GSTAGE(32, 1)
    for (int t = 0; t < 30; t += 3) {
        GSTEP(t, 0, "vmcnt(4)", 1)
        GSTEP(t + 1, 1, "vmcnt(4)", 1)
        GSTEP(t + 2, 2, "vmcnt(4)", 1)
    }
    GSTEP(30, 0, "vmcnt(4)", 0)
    GSTEP(31, 1, "vmcnt(0)", 0)
#undef GSTAGE
#undef GSTEP

    const int rowb = m0 + wr * 64 + (l >> 4) * 4;
    const int colb = n0 + wc * 64 + col16;
    #pragma unroll
    for (int n = 0; n < 4; ++n) {
        int col = colb + n * 16;
        int h = col / 192;
        int rem = col - h * 192;
        int part = rem >> 6, d = rem & 63;   // wave-uniform
        float bv = bias[col];
        #pragma unroll
        for (int m = 0; m < 4; ++m) {
            int r0 = rowb + m * 16;
            int b = r0 >> 11, s0r = r0 & 2047;
            int bh = b * 16 + h;
            if (part == 0) {
                #pragma unroll
                for (int j = 0; j < 4; ++j)
                    Qf[((size_t)bh * 2048 + s0r + j) * 64 + d] =
                        (_Float16)((acc[m][n][j] + bv) * QSCALE);
            } else if (part == 1) {
                #pragma unroll
                for (int j = 0; j < 4; ++j)
                    Kf[((size_t)bh * 2048 + s0r + j) * 64 + d] = (_Float16)(acc[m][n][j] + bv);
            } else {
                half4 pk;
                pk[0] = (_Float16)(acc[m][n][0] + bv);
                pk[1] = (_Float16)(acc[m][n][1] + bv);
                pk[2] = (_Float16)(acc[m][n][2] + bv);
                pk[3] = (_Float16)(acc[m][n][3] + bv);
                *(half4*)&VfT[((size_t)bh * 64 + d) * 2048 + s0r] = pk;
            }
        }
    }
}

// out[M,N] = A[M,K] @ B[N,K]^T + bias, f32 out. 128x64 tile, 3-buffer pipeline.
__global__ __launch_bounds__(256, 2) void gemm_o(
    const _Float16* __restrict__ A, const _Float16* __restrict__ B,
    const float* __restrict__ bias, float* __restrict__ C,
    int M, int N, int K) {
    __shared__ __align__(1024) unsigned char smem[36864];  // 3 x (A 8K + B 4K)
    GEMM_SETUP(K, 64)
    const int rb0 = wc * 32 + col16;
    const int offB = rb0 * 64 + ((kc ^ ((rb0 >> 1) & 3)) * 16);
    f32x4 acc[4][2] = {};

#define OSTAGE(k0_, buf_)                                                              \
    load_lds16(A + gA0 + (k0_), ldsW + (buf_) * 12288 + 0);                            \
    load_lds16(A + gA1 + (k0_), ldsW + (buf_) * 12288 + 4096);                         \
    load_lds16(B + gB0 + (k0_), ldsW + (buf_) * 12288 + 8192);
#define OSTEP(s_, buf_, VM, dostage)                                                   \
    asm volatile("s_waitcnt " VM ::: "memory");                                        \
    __builtin_amdgcn_sched_barrier(0);                                                 \
    __builtin_amdgcn_s_barrier();                                                      \
    if (dostage) { OSTAGE(((s_) + 2) * 32, ((buf_) + 2) % 3) }                         \
    {                                                                                  \
        const unsigned char* bs = smem + (buf_) * 12288;                               \
        half8 af[4], bf[2];                                                            \
        _Pragma("unroll")                                                              \
        for (int m = 0; m < 4; ++m) af[m] = *(const half8*)(bs + offA + m * 1024);     \
        _Pragma("unroll")                                                              \
        for (int n = 0; n < 2; ++n) bf[n] = *(const half8*)(bs + 8192 + offB + n * 1024); \
        _Pragma("unroll")                                                              \
        for (int m = 0; m < 4; ++m)                                                    \
            _Pragma("unroll")                                                          \
            for (int n = 0; n < 2; ++n)                                                \
                acc[m][n] = __builtin_amdgcn_mfma_f32_16x16x32_f16(af[m], bf[n], acc[m][n], 0, 0, 0); \
    }

    OSTAGE(0, 0)
    OSTAGE(32, 1)
    for (int t = 0; t < 30; t += 3) {
        OSTEP(t, 0, "vmcnt(3)", 1)
        OSTEP(t + 1, 1, "vmcnt(3)", 1)
        OSTEP(t + 2, 2, "vmcnt(3)", 1)
    }
    OSTEP(30, 0, "vmcnt(3)", 0)
    OSTEP(31, 1, "vmcnt(0)", 0)
#undef OSTAGE
#undef OSTEP

    const int rowb = m0 + wr * 64 + (l >> 4) * 4;
    const int colb = n0 + wc * 32 + col16;
    float bv[2];
    #pragma unroll
    for (int n = 0; n < 2; ++n) bv[n] = bias[colb + n * 16];
    #pragma unroll
    for (int m = 0; m < 4; ++m)
        #pragma unroll
        for (int j = 0; j < 4; ++j) {
            float* crow = C + (size_t)(rowb + m * 16 + j) * N + colb;
            #pragma unroll
            for (int n = 0; n < 2; ++n) crow[n * 16] = acc[m][n][j] + bv[n];
        }
}

// MFMA flash attention, 32x32 f16, in-register P, absolute-score softmax.
// Straight loop (QK(t)+softmax+PV(t) per iter), 3-buffer K/V, prefetch depth 2,
// counted vmcnt + raw s_barrier (no drain). 8 identical waves, q-tile 256,
// grid remapped so a head's 8 q-blocks share one XCD.
__global__ __launch_bounds__(512, 2) void mfma_attn(
    const _Float16* __restrict__ Qf, const _Float16* __restrict__ Kf,
    const _Float16* __restrict__ VfT, _Float16* __restrict__ vals) {
    __shared__ __align__(1024) unsigned char smem[49152];  // K: buf*8K @0; V: 24K + buf*8K
    const int tid = threadIdx.x;
    const int l = tid & 63, w = tid >> 6;          // 8 waves
    const int l31 = l & 31, hl = l >> 5;
    const int hwbid = blockIdx.y * gridDim.x + blockIdx.x;
    const int q_t = (hwbid >> 3) & 7;
    const int bh = (hwbid & 7) + ((hwbid >> 6) << 3);
    const int q0 = q_t * 256;
    const int h = bh & 15, b = bh >> 4;

    half8 qf[4];
    {
        const _Float16* qp = Qf + ((size_t)bh * 2048 + q0 + w * 32 + l31) * 64 + hl * 8;
        #pragma unroll
        for (int c = 0; c < 4; ++c) qf[c] = *(const half8*)(qp + c * 16);
    }
    f32x16 zvec = {};
    f32x16 o0 = {}, o1 = {};
    float mshift = 0.f, lsum = 0.f;

    const _Float16* Kg = Kf + (size_t)bh * 2048 * 64;
    const _Float16* Vg = VfT + (size_t)bh * 64 * 2048;

    int offK, offV;
    {
        int row2 = w * 4 + (l >> 4);
        int slot = (l & 15) ^ (row2 & 15);
        int row = row2 * 2 + (slot >> 3);
        int chunk = slot & 7;
        offK = row * 64 + chunk * 8;
        offV = row * 2048 + chunk * 8;
    }
    const int sbase = (l31 & 1) * 8;
    const int xr = (l31 >> 1) & 15;
    const int rb0 = (l31 >> 1) * 256;

    #define STAGE(kt0, buf)                                                            \
        {                                                                              \
            unsigned char* bK = smem + (buf) * 8192 + w * 1024;                        \
            unsigned char* bV = smem + 24576 + (buf) * 8192 + w * 1024;                \
            load_lds16(Kg + (size_t)(kt0) * 64 + offK, bK);                            \
            load_lds16(Vg + (kt0) + offV, bV);                                         \
        }

    #define QK_TILE(kb, D0, D1)                                                        \
        {                                                                              \
            const unsigned char* Ksb_ = smem + (kb) * 8192;                            \
            {                                                                          \
                int chOff = ((sbase + hl) ^ xr) << 4;                                  \
                half8 k0_ = *(const half8*)(Ksb_ + rb0 + chOff);                       \
                half8 k1_ = *(const half8*)(Ksb_ + rb0 + 4096 + chOff);                \
                D0 = __builtin_amdgcn_mfma_f32_32x32x16_f16(k0_, qf[0], zvec, 0, 0, 0);\
                D1 = __builtin_amdgcn_mfma_f32_32x32x16_f16(k1_, qf[0], zvec, 0, 0, 0);\
            }                                                                          \
            _Pragma("unroll")                                                          \
            for (int kc = 1; kc < 4; ++kc) {                                           \
                int chOff = ((sbase + kc * 2 + hl) ^ xr) << 4;                         \
                half8 k0_ = *(const half8*)(Ksb_ + rb0 + chOff);                       \
                half8 k1_ = *(const half8*)(Ksb_ + rb0 + 4096 + chOff);                \
                D0 = __builtin_amdgcn_mfma_f32_32x32x16_f16(k0_, qf[kc], D0, 0, 0, 0); \
                D1 = __builtin_amdgcn_mfma_f32_32x32x16_f16(k1_, qf[kc], D1, 0, 0, 0); \
            }                                                                          \
        }

    // softmax + PV on scores S0/S1, V buffer index vb_
    #define SMPV(S0, S1, vb_)                                                          \
        {                                                                              \
            const unsigned char* Vsb_ = smem + 24576 + (vb_) * 8192;                   \
            if (__any(mshift != 0.f)) {                                                \
                _Pragma("unroll")                                                      \
                for (int r = 0; r < 16; ++r) { S0[r] -= mshift; S1[r] -= mshift; }     \
            }                                                                          \
            float r0 = 0.f, r1 = 0.f, r2 = 0.f, r3 = 0.f;                              \
            unsigned int a[2][8];                                                      \
            _Pragma("unroll")                                                          \
            for (int j = 0; j < 8; ++j) {                                              \
                float p0 = __builtin_amdgcn_exp2f(S0[2 * j]);                          \
                float p1 = __builtin_amdgcn_exp2f(S0[2 * j + 1]);                      \
                float q0_ = __builtin_amdgcn_exp2f(S1[2 * j]);                         \
                float q1_ = __builtin_amdgcn_exp2f(S1[2 * j + 1]);                     \
                r0 += p0; r1 += p1; r2 += q0_; r3 += q1_;                              \
                a[0][j] = __builtin_bit_cast(unsigned int, __builtin_amdgcn_cvt_pkrtz(p0, p1));   \
                a[1][j] = __builtin_bit_cast(unsigned int, __builtin_amdgcn_cvt_pkrtz(q0_, q1_)); \
            }                                                                          \
            float rsum = (r0 + r1) + (r2 + r3);                                        \
            if (__any(rsum > 32768.f)) {                                               \
                float pmax = S0[0];                                                    \
                _Pragma("unroll")                                                      \
                for (int r = 1; r < 16; ++r) pmax = fmaxf(pmax, S0[r]);                \
                _Pragma("unroll")                                                      \
                for (int r = 0; r < 16; ++r) pmax = fmaxf(pmax, S1[r]);                \
                pmax = fmaxf(pmax, __shfl_xor(pmax, 32, 64));                          \
                float d_ = fmaxf(pmax, 0.f);                                           \
                float corr = __builtin_amdgcn_exp2f(-d_);                              \
                _Pragma("unroll")                                                      \
                for (int r = 0; r < 16; ++r) { S0[r] -= d_; S1[r] -= d_; }             \
                _Pragma("unroll")                                                      \
                for (int r = 0; r < 16; ++r) { o0[r] *= corr; o1[r] *= corr; }         \
                lsum *= corr;                                                          \
                mshift += d_;                                                          \
                r0 = r1 = r2 = r3 = 0.f;                                               \
                _Pragma("unroll")                                                      \
                for (int j = 0; j < 8; ++j) {                                          \
                    float p0 = __builtin_amdgcn_exp2f(S0[2 * j]);                      \
                    float p1 = __builtin_amdgcn_exp2f(S0[2 * j + 1]);                  \
                    float q0_ = __builtin_amdgcn_exp2f(S1[2 * j]);                     \
                    float q1_ = __builtin_amdgcn_exp2f(S1[2 * j + 1]);                 \
                    r0 += p0; r1 += p1; r2 += q0_; r3 += q1_;                          \
                    a[0][j] = __builtin_bit_cast(unsigned int, __builtin_amdgcn_cvt_pkrtz(p0, p1));   \
                    a[1][j] = __builtin_bit_cast(unsigned int, __builtin_amdgcn_cvt_pkrtz(q0_, q1_)); \
                }                                                                      \
                rsum = (r0 + r1) + (r2 + r3);                                          \
            }                                                                          \
            lsum += rsum;                                                              \
            _Pragma("unroll")                                                          \
            for (int c = 0; c < 2; ++c) {                                              \
                pl32swap(a[c][0], a[c][2]);                                            \
                pl32swap(a[c][1], a[c][3]);                                            \
                pl32swap(a[c][4], a[c][6]);                                            \
                pl32swap(a[c][5], a[c][7]);                                            \
            }                                                                          \
            _Pragma("unroll")                                                          \
            for (int kk = 0; kk < 4; ++kk) {                                           \
                u32x4 pw;                                                              \
                pw.x = a[kk >> 1][(kk & 1) * 4 + 0];                                   \
                pw.y = a[kk >> 1][(kk & 1) * 4 + 1];                                   \
                pw.z = a[kk >> 1][(kk & 1) * 4 + 2];                                   \
                pw.w = a[kk >> 1][(kk & 1) * 4 + 3];                                   \
                half8 pf = __builtin_bit_cast(half8, pw);                              \
                int chOff = ((sbase + kk * 2 + hl) ^ xr) << 4;                         \
                half8 v0 = *(const half8*)(Vsb_ + rb0 + chOff);                        \
                half8 v1 = *(const half8*)(Vsb_ + rb0 + 4096 + chOff);                 \
                o0 = __builtin_amdgcn_mfma_f32_32x32x16_f16(v0, pf, o0, 0, 0, 0);      \
                o1 = __builtin_amdgcn_mfma_f32_32x32x16_f16(v1, pf, o1, 0, 0, 0);      \
            }                                                                          \
        }

    // iter t: vmcnt(in-flight next-tile loads); raw barrier; STAGE(t+2); compute(t)
    #define AITER(tt, kb, VM, dostage)                                                 \
        asm volatile("s_waitcnt " VM ::: "memory");                                    \
        __builtin_amdgcn_sched_barrier(0);                                             \
        __builtin_amdgcn_s_barrier();                                                  \
        if (dostage) STAGE(((tt) + 2) * 64, ((kb) + 2) % 3)                            \
        QK_TILE(kb, sS0, sS1)                                                          \
        SMPV(sS0, sS1, kb)

    STAGE(0, 0)
    STAGE(64, 1)
    f32x16 sS0, sS1;
    for (int t = 0; t < 30; t += 3) {
        AITER(t, 0, "vmcnt(2)", 1)
        AITER(t + 1, 1, "vmcnt(2)", 1)
        AITER(t + 2, 2, "vmcnt(2)", 1)
    }
    AITER(30, 0, "vmcnt(2)", 0)
    AITER(31, 1, "vmcnt(0)", 0)

    // ---- epilogue ----
    lsum += __shfl_xor(lsum, 32, 64);
    float inv = 1.f / lsum;
    size_t orow = ((size_t)(b * 2048 + q0 + w * 32 + l31)) * 1024 + h * 64;
    #pragma unroll
    for (int dc = 0; dc < 2; ++dc) {
        const f32x16* op = dc ? &o1 : &o0;
        #pragma unroll
        for (int rq = 0; rq < 4; ++rq) {
            int d0 = dc * 32 + rq * 8 + hl * 4;
            half4 hv;
            #pragma unroll
            for (int j = 0; j < 4; ++j) hv[j] = (_Float16)((*op)[rq * 4 + j] * inv);
            *(half4*)(vals + orow + d0) = hv;
        }
    }
}

extern "C" void kernel_launch(void* const* d_in, const int* in_sizes, int n_in,
                              void* d_out, int out_size, void* d_ws, size_t ws_size,
                              hipStream_t stream) {
    const float* x     = (const float*)d_in[0];
    const float* w_qkv = (const float*)d_in[1];
    const float* b_qkv = (const float*)d_in[2];
    const float* w_o   = (const float*)d_in[3];
    const float* b_o   = (const float*)d_in[4];
    float* out = (float*)d_out;

    const int B = 2, S = 2048, D = 1024;
    const int M = B * S;          // 4096
    const int N1 = 3 * D;         // 3072
    const int BH = B * NHEADS;    // 32

    _Float16* xf  = (_Float16*)d_ws;                  // [4096,1024]
    _Float16* wqf = xf  + (size_t)M * D;              // [3072,1024]
    _Float16* wof = wqf + (size_t)N1 * D;             // [1024,1024]
    _Float16* Qf  = wof + (size_t)D * D;              // [32,2048,64]
    _Float16* Kf  = Qf  + (size_t)BH * S * HD;
    _Float16* VfT = Kf  + (size_t)BH * S * HD;        // [32,64,2048]
    _Float16* vals = xf;   // reuse x-f16 space after gemm_qkv

    // 0) all f32->f16 conversions in one launch
    cvt_all<<<(NX + NWQ + NWO) / 2048, 256, 0, stream>>>(x, w_qkv, w_o, xf, wqf, wof);

    // 1) fused QKV projection -> f16 attention layouts (counted-vmcnt pipeline)
    gemm_qkv<<<dim3(N1 / 128, M / 128), 256, 0, stream>>>(xf, wqf, b_qkv, Qf, Kf, VfT, D);

    // 2) MFMA flash attention (32x32 f16, counted-vmcnt, XCD-grouped)
    mfma_attn<<<dim3(S / 256, BH), 512, 0, stream>>>(Qf, Kf, VfT, vals);

    // 3) out = vals @ w_o^T + b_o  (128x64 tile, counted-vmcnt pipeline)
    gemm_o<<<dim3(D / 64, M / 128), 256, 0, stream>>>(vals, wof, b_o, out, M, D, D);
}

// Round 15
// 106.788 us; speedup vs baseline: 1.1874x; 1.0041x over previous
//
#include <hip/hip_runtime.h>
#include <math.h>

#define NHEADS 16
#define HD 64

typedef __attribute__((ext_vector_type(8))) _Float16 half8;
typedef __attribute__((ext_vector_type(4))) _Float16 half4;
typedef __attribute__((ext_vector_type(4))) float f32x4;
typedef __attribute__((ext_vector_type(16))) float f32x16;
typedef __attribute__((ext_vector_type(4))) unsigned int u32x4;

__device__ inline void load_lds16(const void* g, void* l) {
    __builtin_amdgcn_global_load_lds(
        (const __attribute__((address_space(1))) unsigned int*)g,
        (__attribute__((address_space(3))) unsigned int*)l, 16, 0, 0);
}
__device__ inline void pl32swap(unsigned int& x, unsigned int& y) {
    asm volatile("v_permlane32_swap_b32 %0, %1" : "+v"(x), "+v"(y));
}

// fp32 -> fp16 for x, w_qkv, w_o in ONE launch. Segment by flat index.
#define NX  4194304   // 4096*1024
#define NWQ 3145728   // 3072*1024
#define NWO 1048576   // 1024*1024
__global__ void cvt_all(const float* __restrict__ x, const float* __restrict__ wq,
                        const float* __restrict__ wo, _Float16* __restrict__ xf,
                        _Float16* __restrict__ wqf, _Float16* __restrict__ wof) {
    int i = (blockIdx.x * blockDim.x + threadIdx.x) * 8;
    const float* src; _Float16* dst; int off;
    if (i < NX)            { src = x;  dst = xf;  off = i; }
    else if (i < NX + NWQ) { src = wq; dst = wqf; off = i - NX; }
    else                   { src = wo; dst = wof; off = i - (NX + NWQ); }
    float4 a = *(const float4*)(src + off);
    float4 b = *(const float4*)(src + off + 4);
    half8 h;
    h[0] = (_Float16)a.x; h[1] = (_Float16)a.y; h[2] = (_Float16)a.z; h[3] = (_Float16)a.w;
    h[4] = (_Float16)b.x; h[5] = (_Float16)b.y; h[6] = (_Float16)b.z; h[7] = (_Float16)b.w;
    *(half8*)(dst + off) = h;
}

// ---- common GEMM prologue (index math), 128-row A, parameterizable N-tile ----
#define GEMM_SETUP(K, NTILE)                                                           \
    const int tid = threadIdx.x;                                                       \
    const int l = tid & 63, w = tid >> 6;                                              \
    const int wr = w >> 1, wc = w & 1;                                                 \
    const int nwg = gridDim.x * gridDim.y;                                             \
    const int bid = blockIdx.y * gridDim.x + blockIdx.x;                               \
    const int swz = (bid & 7) * (nwg >> 3) + (bid >> 3);                               \
    const int m0 = (swz / gridDim.x) * 128, n0 = (swz % gridDim.x) * (NTILE);          \
    const int srow = tid >> 2;                                                         \
    const int schunk = (tid & 3) ^ ((srow >> 1) & 3);                                  \
    const size_t gA0 = (size_t)(m0 + srow) * K + schunk * 8;                           \
    const size_t gA1 = gA0 + (size_t)64 * K;                                           \
    const size_t gB0 = (size_t)(n0 + srow) * K + schunk * 8;                           \
    unsigned char* ldsW = smem + w * 1024;                                             \
    const int col16 = l & 15, kc = l >> 4;                                             \
    const int ra0 = wr * 64 + col16;                                                   \
    const int offA = ra0 * 64 + ((kc ^ ((ra0 >> 1) & 3)) * 16);

// QKV GEMM: 128x128 tile, K=1024 (32 steps), 3-buffer counted-vmcnt pipeline.
#define QSCALE 0.18033688f
__global__ __launch_bounds__(256, 2) void gemm_qkv(
    const _Float16* __restrict__ A, const _Float16* __restrict__ B,
    const float* __restrict__ bias,
    _Float16* __restrict__ Qf, _Float16* __restrict__ Kf,
    _Float16* __restrict__ VfT, int K) {
    __shared__ __align__(1024) unsigned char smem[49152];  // 3 x (A 8K + B 8K)
    GEMM_SETUP(K, 128)
    const size_t gB1 = gB0 + (size_t)64 * K;
    const int rb0 = wc * 64 + col16;
    const int offB = rb0 * 64 + ((kc ^ ((rb0 >> 1) & 3)) * 16);
    f32x4 acc[4][4] = {};

#define GSTAGE(k0_, buf_)                                                              \
    load_lds16(A + gA0 + (k0_), ldsW + (buf_) * 16384 + 0);                            \
    load_lds16(A + gA1 + (k0_), ldsW + (buf_) * 16384 + 4096);                         \
    load_lds16(B + gB0 + (k0_), ldsW + (buf_) * 16384 + 8192);                         \
    load_lds16(B + gB1 + (k0_), ldsW + (buf_) * 16384 + 12288);
#define GSTEP(s_, buf_, VM, dostage)                                                   \
    asm volatile("s_waitcnt " VM ::: "memory");                                        \
    __builtin_amdgcn_sched_barrier(0);                                                 \
    __builtin_amdgcn_s_barrier();                                                      \
    if (dostage) { GSTAGE(((s_) + 2) * 32, ((buf_) + 2) % 3) }                         \
    {                                                                                  \
        const unsigned char* bs = smem + (buf_) * 16384;                               \
        half8 af[4], bf[4];                                                            \
        _Pragma("unroll")                                                              \
        for (int m = 0; m < 4; ++m) af[m] = *(const half8*)(bs + offA + m * 1024);     \
        _Pragma("unroll")                                                              \
        for (int n = 0; n < 4; ++n) bf[n] = *(const half8*)(bs + 8192 + offB + n * 1024); \
        _Pragma("unroll")                                                              \
        for (int m = 0; m < 4; ++m)                                                    \
            _Pragma("unroll")                                                          \
            for (int n = 0; n < 4; ++n)                                                \
                acc[m][n] = __builtin_amdgcn_mfma_f32_16x16x32_f16(af[m], bf[n], acc[m][n], 0, 0, 0); \
    }

    GSTAGE(0, 0)
    GSTAGE(32, 1)
    for (int t = 0; t < 30; t += 3) {
        GSTEP(t, 0, "vmcnt(4)", 1)
        GSTEP(t + 1, 1, "vmcnt(4)", 1)
        GSTEP(t + 2, 2, "vmcnt(4)", 1)
    }
    GSTEP(30, 0, "vmcnt(4)", 0)
    GSTEP(31, 1, "vmcnt(0)", 0)
#undef GSTAGE
#undef GSTEP

    const int rowb = m0 + wr * 64 + (l >> 4) * 4;
    const int colb = n0 + wc * 64 + col16;
    #pragma unroll
    for (int n = 0; n < 4; ++n) {
        int col = colb + n * 16;
        int h = col / 192;
        int rem = col - h * 192;
        int part = rem >> 6, d = rem & 63;   // wave-uniform
        float bv = bias[col];
        #pragma unroll
        for (int m = 0; m < 4; ++m) {
            int r0 = rowb + m * 16;
            int b = r0 >> 11, s0r = r0 & 2047;
            int bh = b * 16 + h;
            if (part == 0) {
                #pragma unroll
                for (int j = 0; j < 4; ++j)
                    Qf[((size_t)bh * 2048 + s0r + j) * 64 + d] =
                        (_Float16)((acc[m][n][j] + bv) * QSCALE);
            } else if (part == 1) {
                #pragma unroll
                for (int j = 0; j < 4; ++j)
                    Kf[((size_t)bh * 2048 + s0r + j) * 64 + d] = (_Float16)(acc[m][n][j] + bv);
            } else {
                half4 pk;
                pk[0] = (_Float16)(acc[m][n][0] + bv);
                pk[1] = (_Float16)(acc[m][n][1] + bv);
                pk[2] = (_Float16)(acc[m][n][2] + bv);
                pk[3] = (_Float16)(acc[m][n][3] + bv);
                *(half4*)&VfT[((size_t)bh * 64 + d) * 2048 + s0r] = pk;
            }
        }
    }
}

// out[M,N] = A[M,K] @ B[N,K]^T + bias, f32 out. 128x64 tile, 3-buffer pipeline.
__global__ __launch_bounds__(256, 2) void gemm_o(
    const _Float16* __restrict__ A, const _Float16* __restrict__ B,
    const float* __restrict__ bias, float* __restrict__ C,
    int M, int N, int K) {
    __shared__ __align__(1024) unsigned char smem[36864];  // 3 x (A 8K + B 4K)
    GEMM_SETUP(K, 64)
    const int rb0 = wc * 32 + col16;
    const int offB = rb0 * 64 + ((kc ^ ((rb0 >> 1) & 3)) * 16);
    f32x4 acc[4][2] = {};

#define OSTAGE(k0_, buf_)                                                              \
    load_lds16(A + gA0 + (k0_), ldsW + (buf_) * 12288 + 0);                            \
    load_lds16(A + gA1 + (k0_), ldsW + (buf_) * 12288 + 4096);                         \
    load_lds16(B + gB0 + (k0_), ldsW + (buf_) * 12288 + 8192);
#define OSTEP(s_, buf_, VM, dostage)                                                   \
    asm volatile("s_waitcnt " VM ::: "memory");                                        \
    __builtin_amdgcn_sched_barrier(0);                                                 \
    __builtin_amdgcn_s_barrier();                                                      \
    if (dostage) { OSTAGE(((s_) + 2) * 32, ((buf_) + 2) % 3) }                         \
    {                                                                                  \
        const unsigned char* bs = smem + (buf_) * 12288;                               \
        half8 af[4], bf[2];                                                            \
        _Pragma("unroll")                                                              \
        for (int m = 0; m < 4; ++m) af[m] = *(const half8*)(bs + offA + m * 1024);     \
        _Pragma("unroll")                                                              \
        for (int n = 0; n < 2; ++n) bf[n] = *(const half8*)(bs + 8192 + offB + n * 1024); \
        _Pragma("unroll")                                                              \
        for (int m = 0; m < 4; ++m)                                                    \
            _Pragma("unroll")                                                          \
            for (int n = 0; n < 2; ++n)                                                \
                acc[m][n] = __builtin_amdgcn_mfma_f32_16x16x32_f16(af[m], bf[n], acc[m][n], 0, 0, 0); \
    }

    OSTAGE(0, 0)
    OSTAGE(32, 1)
    for (int t = 0; t < 30; t += 3) {
        OSTEP(t, 0, "vmcnt(3)", 1)
        OSTEP(t + 1, 1, "vmcnt(3)", 1)
        OSTEP(t + 2, 2, "vmcnt(3)", 1)
    }
    OSTEP(30, 0, "vmcnt(3)", 0)
    OSTEP(31, 1, "vmcnt(0)", 0)
#undef OSTAGE
#undef OSTEP

    const int rowb = m0 + wr * 64 + (l >> 4) * 4;
    const int colb = n0 + wc * 32 + col16;
    float bv[2];
    #pragma unroll
    for (int n = 0; n < 2; ++n) bv[n] = bias[colb + n * 16];
    #pragma unroll
    for (int m = 0; m < 4; ++m)
        #pragma unroll
        for (int j = 0; j < 4; ++j) {
            float* crow = C + (size_t)(rowb + m * 16 + j) * N + colb;
            #pragma unroll
            for (int n = 0; n < 2; ++n) crow[n * 16] = acc[m][n][j] + bv[n];
        }
}

// MFMA flash attention, 32x32 f16, in-register P, absolute-score softmax.
// PAIRED-TILE ILP: each barrier processes tiles (2p, 2p+1); issue order
// QK(A), QK(B), SM+PV(A), SM+PV(B) -> MFMA pipe drains one tile while VALU/TRANS
// runs the other. 6 LDS tile-slots (3 pair-slots), counted vmcnt, q-tile 256.
__global__ __launch_bounds__(512, 2) void mfma_attn(
    const _Float16* __restrict__ Qf, const _Float16* __restrict__ Kf,
    const _Float16* __restrict__ VfT, _Float16* __restrict__ vals) {
    __shared__ __align__(1024) unsigned char smem[98304];  // K slots 0..5 @ i*8K; V @ 48K + i*8K
    const int tid = threadIdx.x;
    const int l = tid & 63, w = tid >> 6;          // 8 waves
    const int l31 = l & 31, hl = l >> 5;
    const int hwbid = blockIdx.y * gridDim.x + blockIdx.x;
    const int q_t = (hwbid >> 3) & 7;
    const int bh = (hwbid & 7) + ((hwbid >> 6) << 3);
    const int q0 = q_t * 256;
    const int h = bh & 15, b = bh >> 4;

    half8 qf[4];
    {
        const _Float16* qp = Qf + ((size_t)bh * 2048 + q0 + w * 32 + l31) * 64 + hl * 8;
        #pragma unroll
        for (int c = 0; c < 4; ++c) qf[c] = *(const half8*)(qp + c * 16);
    }
    f32x16 zvec = {};
    f32x16 o0 = {}, o1 = {};
    float mshift = 0.f, lsum = 0.f;

    const _Float16* Kg = Kf + (size_t)bh * 2048 * 64;
    const _Float16* Vg = VfT + (size_t)bh * 64 * 2048;

    int offK, offV;
    {
        int row2 = w * 4 + (l >> 4);
        int slot = (l & 15) ^ (row2 & 15);
        int row = row2 * 2 + (slot >> 3);
        int chunk = slot & 7;
        offK = row * 64 + chunk * 8;
        offV = row * 2048 + chunk * 8;
    }
    const int sbase = (l31 & 1) * 8;
    const int xr = (l31 >> 1) & 15;
    const int rb0 = (l31 >> 1) * 256;

    // stage pair p_ (tiles p_*2, p_*2+1) into slots 2*(p_%3), 2*(p_%3)+1
    #define STAGE_PAIR(p_)                                                             \
        {                                                                              \
            int kt0_ = (p_) * 128;                                                     \
            int s0_ = 2 * ((p_) % 3);                                                  \
            unsigned char* bK0 = smem + s0_ * 8192 + w * 1024;                         \
            unsigned char* bV0 = smem + 49152 + s0_ * 8192 + w * 1024;                 \
            load_lds16(Kg + (size_t)kt0_ * 64 + offK, bK0);                            \
            load_lds16(Vg + kt0_ + offV, bV0);                                         \
            load_lds16(Kg + (size_t)(kt0_ + 64) * 64 + offK, bK0 + 8192);              \
            load_lds16(Vg + (kt0_ + 64) + offV, bV0 + 8192);                           \
        }

    #define QK_TILE(slot_, D0, D1)                                                     \
        {                                                                              \
            const unsigned char* Ksb_ = smem + (slot_) * 8192;                         \
            {                                                                          \
                int chOff = ((sbase + hl) ^ xr) << 4;                                  \
                half8 k0_ = *(const half8*)(Ksb_ + rb0 + chOff);                       \
                half8 k1_ = *(const half8*)(Ksb_ + rb0 + 4096 + chOff);                \
                D0 = __builtin_amdgcn_mfma_f32_32x32x16_f16(k0_, qf[0], zvec, 0, 0, 0);\
                D1 = __builtin_amdgcn_mfma_f32_32x32x16_f16(k1_, qf[0], zvec, 0, 0, 0);\
            }                                                                          \
            _Pragma("unroll")                                                          \
            for (int kc = 1; kc < 4; ++kc) {                                           \
                int chOff = ((sbase + kc * 2 + hl) ^ xr) << 4;                         \
                half8 k0_ = *(const half8*)(Ksb_ + rb0 + chOff);                       \
                half8 k1_ = *(const half8*)(Ksb_ + rb0 + 4096 + chOff);                \
                D0 = __builtin_amdgcn_mfma_f32_32x32x16_f16(k0_, qf[kc], D0, 0, 0, 0); \
                D1 = __builtin_amdgcn_mfma_f32_32x32x16_f16(k1_, qf[kc], D1, 0, 0, 0); \
            }                                                                          \
        }

    // softmax + PV on scores S0/S1, V slot slot_
    #define SMPV(S0, S1, slot_)                                                        \
        {                                                                              \
            const unsigned char* Vsb_ = smem + 49152 + (slot_) * 8192;                 \
            if (__any(mshift != 0.f)) {                                                \
                _Pragma("unroll")                                                      \
                for (int r = 0; r < 16; ++r) { S0[r] -= mshift; S1[r] -= mshift; }     \
            }                                                                          \
            float r0 = 0.f, r1 = 0.f, r2 = 0.f, r3 = 0.f;                              \
            unsigned int a[2][8];                                                      \
            _Pragma("unroll")                                                          \
            for (int j = 0; j < 8; ++j) {                                              \
                float p0 = __builtin_amdgcn_exp2f(S0[2 * j]);                          \
                float p1 = __builtin_amdgcn_exp2f(S0[2 * j + 1]);                      \
                float q0_ = __builtin_amdgcn_exp2f(S1[2 * j]);                         \
                float q1_ = __builtin_amdgcn_exp2f(S1[2 * j + 1]);                     \
                r0 += p0; r1 += p1; r2 += q0_; r3 += q1_;                              \
                a[0][j] = __builtin_bit_cast(unsigned int, __builtin_amdgcn_cvt_pkrtz(p0, p1));   \
                a[1][j] = __builtin_bit_cast(unsigned int, __builtin_amdgcn_cvt_pkrtz(q0_, q1_)); \
            }                                                                          \
            float rsum = (r0 + r1) + (r2 + r3);                                        \
            if (__any(rsum > 32768.f)) {                                               \
                float pmax = S0[0];                                                    \
                _Pragma("unroll")                                                      \
                for (int r = 1; r < 16; ++r) pmax = fmaxf(pmax, S0[r]);                \
                _Pragma("unroll")                                                      \
                for (int r = 0; r < 16; ++r) pmax = fmaxf(pmax, S1[r]);                \
                pmax = fmaxf(pmax, __shfl_xor(pmax, 32, 64));                          \
                float d_ = fmaxf(pmax, 0.f);                                           \
                float corr = __builtin_amdgcn_exp2f(-d_);                              \
                _Pragma("unroll")                                                      \
                for (int r = 0; r < 16; ++r) { S0[r] -= d_; S1[r] -= d_; }             \
                _Pragma("unroll")                                                      \
                for (int r = 0; r < 16; ++r) { o0[r] *= corr; o1[r] *= corr; }         \
                lsum *= corr;                                                          \
                mshift += d_;                                                          \
                r0 = r1 = r2 = r3 = 0.f;                                               \
                _Pragma("unroll")                                                      \
                for (int j = 0; j < 8; ++j) {                                          \
                    float p0 = __builtin_amdgcn_exp2f(S0[2 * j]);                      \
                    float p1 = __builtin_amdgcn_exp2f(S0[2 * j + 1]);                  \
                    float q0_ = __builtin_amdgcn_exp2f(S1[2 * j]);                     \
                    float q1_ = __builtin_amdgcn_exp2f(S1[2 * j + 1]);                 \
                    r0 += p0; r1 += p1; r2 += q0_; r3 += q1_;                          \
                    a[0][j] = __builtin_bit_cast(unsigned int, __builtin_amdgcn_cvt_pkrtz(p0, p1));   \
                    a[1][j] = __builtin_bit_cast(unsigned int, __builtin_amdgcn_cvt_pkrtz(q0_, q1_)); \
                }                                                                      \
                rsum = (r0 + r1) + (r2 + r3);                                          \
            }                                                                          \
            lsum += rsum;                                                              \
            _Pragma("unroll")                                                          \
            for (int c = 0; c < 2; ++c) {                                              \
                pl32swap(a[c][0], a[c][2]);                                            \
                pl32swap(a[c][1], a[c][3]);                                            \
                pl32swap(a[c][4], a[c][6]);                                            \
                pl32swap(a[c][5], a[c][7]);                                            \
            }                                                                          \
            _Pragma("unroll")                                                          \
            for (int kk = 0; kk < 4; ++kk) {                                           \
                u32x4 pw;                                                              \
                pw.x = a[kk >> 1][(kk & 1) * 4 + 0];                                   \
                pw.y = a[kk >> 1][(kk & 1) * 4 + 1];                                   \
                pw.z = a[kk >> 1][(kk & 1) * 4 + 2];                                   \
                pw.w = a[kk >> 1][(kk & 1) * 4 + 3];                                   \
                half8 pf = __builtin_bit_cast(half8, pw);                              \
                int chOff = ((sbase + kk * 2 + hl) ^ xr) << 4;                         \
                half8 v0 = *(const half8*)(Vsb_ + rb0 + chOff);                        \
                half8 v1 = *(const half8*)(Vsb_ + rb0 + 4096 + chOff);                 \
                o0 = __builtin_amdgcn_mfma_f32_32x32x16_f16(v0, pf, o0, 0, 0, 0);      \
                o1 = __builtin_amdgcn_mfma_f32_32x32x16_f16(v1, pf, o1, 0, 0, 0);      \
            }                                                                          \
        }

    // pair-iter p: wait pair p's loads (next pair's 4 stay in flight); barrier;
    // STAGE(p+2); QK both tiles; SM+PV both tiles.
    #define PITER(p_, sl_, VM, dostage)                                                \
        asm volatile("s_waitcnt " VM ::: "memory");                                    \
        __builtin_amdgcn_sched_barrier(0);                                             \
        __builtin_amdgcn_s_barrier();                                                  \
        if (dostage) STAGE_PAIR((p_) + 2)                                              \
        QK_TILE(2 * (sl_), sA0, sA1)                                                   \
        QK_TILE(2 * (sl_) + 1, sB0, sB1)                                               \
        SMPV(sA0, sA1, 2 * (sl_))                                                      \
        SMPV(sB0, sB1, 2 * (sl_) + 1)

    STAGE_PAIR(0)
    STAGE_PAIR(1)
    f32x16 sA0, sA1, sB0, sB1;
    for (int p = 0; p < 12; p += 3) {
        PITER(p, 0, "vmcnt(4)", 1)
        PITER(p + 1, 1, "vmcnt(4)", 1)
        PITER(p + 2, 2, "vmcnt(4)", 1)
    }
    PITER(12, 0, "vmcnt(4)", 1)
    PITER(13, 1, "vmcnt(4)", 1)
    PITER(14, 2, "vmcnt(4)", 0)
    PITER(15, 0, "vmcnt(0)", 0)

    // ---- epilogue ----
    lsum += __shfl_xor(lsum, 32, 64);
    float inv = 1.f / lsum;
    size_t orow = ((size_t)(b * 2048 + q0 + w * 32 + l31)) * 1024 + h * 64;
    #pragma unroll
    for (int dc = 0; dc < 2; ++dc) {
        const f32x16* op = dc ? &o1 : &o0;
        #pragma unroll
        for (int rq = 0; rq < 4; ++rq) {
            int d0 = dc * 32 + rq * 8 + hl * 4;
            half4 hv;
            #pragma unroll
            for (int j = 0; j < 4; ++j) hv[j] = (_Float16)((*op)[rq * 4 + j] * inv);
            *(half4*)(vals + orow + d0) = hv;
        }
    }
}

extern "C" void kernel_launch(void* const* d_in, const int* in_sizes, int n_in,
                              void* d_out, int out_size, void* d_ws, size_t ws_size,
                              hipStream_t stream) {
    const float* x     = (const float*)d_in[0];
    const float* w_qkv = (const float*)d_in[1];
    const float* b_qkv = (const float*)d_in[2];
    const float* w_o   = (const float*)d_in[3];
    const float* b_o   = (const float*)d_in[4];
    float* out = (float*)d_out;

    const int B = 2, S = 2048, D = 1024;
    const int M = B * S;          // 4096
    const int N1 = 3 * D;         // 3072
    const int BH = B * NHEADS;    // 32

    _Float16* xf  = (_Float16*)d_ws;                  // [4096,1024]
    _Float16* wqf = xf  + (size_t)M * D;              // [3072,1024]
    _Float16* wof = wqf + (size_t)N1 * D;             // [1024,1024]
    _Float16* Qf  = wof + (size_t)D * D;              // [32,2048,64]
    _Float16* Kf  = Qf  + (size_t)BH * S * HD;
    _Float16* VfT = Kf  + (size_t)BH * S * HD;        // [32,64,2048]
    _Float16* vals = xf;   // reuse x-f16 space after gemm_qkv

    // 0) all f32->f16 conversions in one launch
    cvt_all<<<(NX + NWQ + NWO) / 2048, 256, 0, stream>>>(x, w_qkv, w_o, xf, wqf, wof);

    // 1) fused QKV projection -> f16 attention layouts (counted-vmcnt pipeline)
    gemm_qkv<<<dim3(N1 / 128, M / 128), 256, 0, stream>>>(xf, wqf, b_qkv, Qf, Kf, VfT, D);

    // 2) MFMA flash attention (32x32 f16, paired-tile ILP, counted-vmcnt)
    mfma_attn<<<dim3(S / 256, BH), 512, 0, stream>>>(Qf, Kf, VfT, vals);

    // 3) out = vals @ w_o^T + b_o  (128x64 tile, counted-vmcnt pipeline)
    gemm_o<<<dim3(D / 64, M / 128), 256, 0, stream>>>(vals, wof, b_o, out, M, D, D);
}